// Round 19
// baseline (246.485 us; speedup 1.0000x reference)
//
#include <hip/hip_runtime.h>
#include <hip/hip_bf16.h>

typedef __bf16 bf16_t;
typedef __bf16 bf16x8 __attribute__((ext_vector_type(8)));
typedef __bf16 bf16x4 __attribute__((ext_vector_type(4)));
typedef float f32x4 __attribute__((ext_vector_type(4)));
typedef float f32x16 __attribute__((ext_vector_type(16)));
typedef unsigned u32x4v __attribute__((ext_vector_type(4)));

#define MFMA16(a, b, c) __builtin_amdgcn_mfma_f32_16x16x32_bf16(a, b, c, 0, 0, 0)
#define MFMA32(a, b, c) __builtin_amdgcn_mfma_f32_32x32x16_bf16(a, b, c, 0, 0, 0)

__device__ __forceinline__ void async_copy16(const void* g, void* l) {
  __builtin_amdgcn_global_load_lds(
      (const __attribute__((address_space(1))) void*)g,
      (__attribute__((address_space(3))) void*)l, 16, 0, 0);
}

__device__ __forceinline__ unsigned cvtpk(float lo, float hi) {
  unsigned r;
  asm("v_cvt_pk_bf16_f32 %0, %1, %2" : "=v"(r) : "v"(lo), "v"(hi));
  return r;
}

// ---------------- fused cast f32 -> bf16 for all three inputs ----------------
__global__ void cast_all(const float* __restrict__ x, const float* __restrict__ wqkv,
                         const float* __restrict__ wproj, bf16_t* __restrict__ xb,
                         bf16_t* __restrict__ wqkvb, bf16_t* __restrict__ wprojb) {
  int stride = gridDim.x * blockDim.x;
  for (int i = blockIdx.x * blockDim.x + threadIdx.x; i < 3145728; i += stride) {
    const float* src;
    bf16_t* dst;
    int idx;
    if (i < 1048576) { src = x; dst = xb; idx = i; }
    else if (i < 2621440) { src = wqkv; dst = wqkvb; idx = i - 1048576; }
    else { src = wproj; dst = wprojb; idx = i - 2621440; }
    const float* p = src + (size_t)idx * 8;
    f32x4 a = *(const f32x4*)p;
    f32x4 b = *(const f32x4*)(p + 4);
    bf16x8 o;
    o[0] = (bf16_t)a[0]; o[1] = (bf16_t)a[1]; o[2] = (bf16_t)a[2]; o[3] = (bf16_t)a[3];
    o[4] = (bf16_t)b[0]; o[5] = (bf16_t)b[1]; o[6] = (bf16_t)b[2]; o[7] = (bf16_t)b[3];
    *(bf16x8*)(dst + (size_t)idx * 8) = o;
  }
}

// ======== FUSED QKV GEMM: one 512-block dispatch ========
// bid <  256: 256x256 4-phase QK-GEMM with fused RoPE epilogue (R16 body)
// bid >= 256: 256x128 depth-2 V-GEMM with V^T transpose epilogue (R6 body)
__global__ __launch_bounds__(512, 1) void gemm_fused(
    const bf16_t* __restrict__ A, const bf16_t* __restrict__ Bw,
    bf16_t* __restrict__ qo, bf16_t* __restrict__ ko, bf16_t* __restrict__ vto,
    int K) {
  __shared__ __align__(16) char lds[147456];
  int tid = threadIdx.x;
  int w = tid >> 6, lane = tid & 63;
  int mr = lane & 15, kg = lane >> 4;
  int bid = blockIdx.x;

  if (bid < 256) {
    // ================= QK path (gemm_qkv verbatim) =================
    int wm = w & 1, wn = w >> 1;
    int chunk = bid & 7, i = bid >> 3;
    int by = (chunk & 3) * 4 + (i & 3);
    int bx = (chunk >> 2) * 8 + (i >> 2);
    int row0 = by * 256, col0 = bx * 256;

    int lr = tid >> 3, ch = (tid & 7) ^ (lr & 7);
    size_t aoff[4], boff[4];
#pragma unroll
    for (int g = 0; g < 4; ++g) {
      int gr = g * 32 + (lr & 31) + (lr >> 5) * 128;
      aoff[g] = (size_t)(row0 + gr) * K + ch * 8;
    }
#pragma unroll
    for (int p = 0; p < 4; ++p) {
      int gr = (lr >> 4) * 64 + p * 16 + (lr & 15);
      boff[p] = (size_t)(col0 + gr) * K + ch * 8;
    }

    auto stgA = [&](int q, int g, int kt) {
      async_copy16(A + aoff[g] + kt * 64, lds + q * 65536 + g * 8192 + tid * 16);
    };
    auto stgB = [&](int q, int p, int kt) {
      async_copy16(Bw + boff[p] + kt * 64, lds + q * 65536 + 32768 + p * 8192 + tid * 16);
    };

    f32x4 zero = {0.f, 0.f, 0.f, 0.f};
    f32x4 acc[8][4];
#pragma unroll
    for (int mi = 0; mi < 8; ++mi)
#pragma unroll
      for (int ni = 0; ni < 4; ++ni) acc[mi][ni] = zero;

    int nt = K >> 6;  // 32

    stgB(0, 0, 0); stgB(0, 1, 0); stgB(0, 2, 0); stgB(0, 3, 0);
    stgA(0, 0, 0); stgA(0, 1, 0); stgA(0, 2, 0); stgA(0, 3, 0);
    asm volatile("s_waitcnt vmcnt(0)" ::: "memory");
    __builtin_amdgcn_sched_barrier(0);
    __builtin_amdgcn_s_barrier();
    __builtin_amdgcn_sched_barrier(0);

#pragma unroll 1
    for (int t = 0; t < nt; ++t) {
      int q = t & 1, qn = q ^ 1;
      int kt = (t + 1 < nt) ? (t + 1) : t;
      const char* Ab = lds + q * 65536;
      const char* Bb = Ab + 32768;
      bf16x8 bf[4][2];

#define QKV_PHASE(MI0, STG, DOWAIT)                                             \
      {                                                                         \
        int r0 = ((MI0) >> 1) * 64 + wm * 32 + mr;                              \
        int r1 = r0 + 16;                                                       \
        bf16x8 a00 = *(const bf16x8*)(Ab + r0 * 128 + ((kg * 16) ^ ((r0 & 7) << 4)));      \
        bf16x8 a01 = *(const bf16x8*)(Ab + r0 * 128 + ((64 + kg * 16) ^ ((r0 & 7) << 4))); \
        bf16x8 a10 = *(const bf16x8*)(Ab + r1 * 128 + ((kg * 16) ^ ((r1 & 7) << 4)));      \
        bf16x8 a11 = *(const bf16x8*)(Ab + r1 * 128 + ((64 + kg * 16) ^ ((r1 & 7) << 4))); \
        STG;                                                                    \
        __builtin_amdgcn_sched_barrier(0);                                      \
        if (DOWAIT) { asm volatile("s_waitcnt vmcnt(4)" ::: "memory"); }        \
        __builtin_amdgcn_s_barrier();                                           \
        asm volatile("s_waitcnt lgkmcnt(0)" ::: "memory");                      \
        __builtin_amdgcn_sched_barrier(0);                                      \
        __builtin_amdgcn_s_setprio(1);                                          \
        _Pragma("unroll")                                                       \
        for (int ni = 0; ni < 4; ++ni) {                                        \
          acc[MI0][ni] = MFMA16(a00, bf[ni][0], acc[MI0][ni]);                  \
          acc[MI0][ni] = MFMA16(a01, bf[ni][1], acc[MI0][ni]);                  \
          acc[(MI0) + 1][ni] = MFMA16(a10, bf[ni][0], acc[(MI0) + 1][ni]);      \
          acc[(MI0) + 1][ni] = MFMA16(a11, bf[ni][1], acc[(MI0) + 1][ni]);      \
        }                                                                       \
        __builtin_amdgcn_s_setprio(0);                                          \
        __builtin_amdgcn_sched_barrier(0);                                      \
        __builtin_amdgcn_s_barrier();                                           \
        __builtin_amdgcn_sched_barrier(0);                                      \
      }

#pragma unroll
      for (int ni = 0; ni < 4; ++ni) {
        int rb = ni * 64 + wn * 16 + mr;
        bf[ni][0] = *(const bf16x8*)(Bb + rb * 128 + ((kg * 16) ^ ((rb & 7) << 4)));
        bf[ni][1] = *(const bf16x8*)(Bb + rb * 128 + ((64 + kg * 16) ^ ((rb & 7) << 4)));
      }
      QKV_PHASE(0, (stgA(qn, 0, kt), stgA(qn, 1, kt), stgB(qn, 0, kt), stgB(qn, 1, kt)), 1)
      QKV_PHASE(2, (stgA(qn, 2, kt), stgA(qn, 3, kt), stgB(qn, 2, kt), stgB(qn, 3, kt)), 0)
      QKV_PHASE(4, (void)0, 0)
      QKV_PHASE(6, (void)0, 0)
#undef QKV_PHASE
    }
    asm volatile("s_waitcnt vmcnt(0)" ::: "memory");
    __syncthreads();

    // ---- fused RoPE epilogue (q pre-scaled) ----
    char* tb = &lds[0];
    int s = col0 >> 11;
    int h0 = (col0 >> 7) & 15;
    int b = row0 >> 11, t0 = row0 & 2047;
#pragma unroll
    for (int mi = 0; mi < 8; ++mi)
#pragma unroll
      for (int ni = 0; ni < 4; ++ni)
#pragma unroll
        for (int jj = 0; jj < 4; ++jj) {
          int rl = wm * 128 + mi * 16 + kg * 4 + jj;
          int cb = (wn * 64 + ni * 16 + mr) * 2;
          *(bf16_t*)(tb + rl * 512 + (cb ^ ((rl & 7) << 4))) = (bf16_t)acc[mi][ni][jj];
        }
    __syncthreads();
    int r = tid >> 1, hs = tid & 1;
    const char* rowb = tb + r * 512;
    int sz = (r & 7) << 4;
    int t = t0 + r;
    bf16_t* dst = (s == 0 ? qo : ko) + ((size_t)((b * 16 + h0 + hs) * 2048 + t)) * 128;
    float tf = (float)t;
    const float cinv = -0.20762050593046014f;  // -log2(10000)/64
    float postm = (s == 0) ? 0.12751744f : 1.0f;
    bf16x8 vin[16];
#pragma unroll
    for (int m = 0; m < 16; ++m)
      vin[m] = *(const bf16x8*)(rowb + ((hs * 256 + m * 16) ^ sz));
#pragma unroll
    for (int m = 0; m < 8; ++m) {
      bf16x8 o1, o2;
#pragma unroll
      for (int e = 0; e < 8; ++e) {
        float ang = tf * exp2f((float)(m * 8 + e) * cinv);
        float sv = __sinf(ang), cv = __cosf(ang);
        float x1 = (float)vin[m][e], x2 = (float)vin[m + 8][e];
        o1[e] = (bf16_t)((x1 * cv - x2 * sv) * postm);
        o2[e] = (bf16_t)((x2 * cv + x1 * sv) * postm);
      }
      *(bf16x8*)(dst + m * 8) = o1;
      *(bf16x8*)(dst + 64 + m * 8) = o2;
    }
  } else {
    // ================= V path (gemm256 MODE 1 verbatim) =================
    int wm = w >> 1, wn = w & 1;
    const bf16_t* Bv = Bw + (size_t)4096 * K;   // v rows of w_qkv
    int vid = bid - 256;
    int wgid = (vid & 7) * 32 + (vid >> 3);
    int by = wgid % 16, bx = wgid / 16;
    int row0 = by * 256, col0 = 4096 + bx * 128;

    size_t aoff[4], boff[2];
#pragma unroll
    for (int it = 0; it < 4; ++it) {
      int c = tid + it * 512;
      int r = c >> 3;
      int chs = (c & 7) ^ (r & 7);
      aoff[it] = (size_t)(row0 + r) * K + chs * 8;
    }
#pragma unroll
    for (int it = 0; it < 2; ++it) {
      int c = tid + it * 512;
      int r = c >> 3;
      int chs = (c & 7) ^ (r & 7);
      boff[it] = (size_t)(col0 - 4096 + r) * K + chs * 8;
    }

    auto stageA = [&](int buf, int kt, int half) {
      char* Ad = &lds[buf * 49152];
#pragma unroll
      for (int it = half * 2; it < half * 2 + 2; ++it)
        async_copy16(A + aoff[it] + kt * 64, Ad + (tid + it * 512) * 16);
    };
    auto stageB = [&](int buf, int kt) {
      char* Bd = &lds[buf * 49152 + 32768];
#pragma unroll
      for (int it = 0; it < 2; ++it)
        async_copy16(Bv + boff[it] + kt * 64, Bd + (tid + it * 512) * 16);
    };

    f32x4 zero = {0.f, 0.f, 0.f, 0.f};
    f32x4 acc[4][4];
#pragma unroll
    for (int mi = 0; mi < 4; ++mi)
#pragma unroll
      for (int ni = 0; ni < 4; ++ni) acc[mi][ni] = zero;

    int nt = K >> 6;
    stageA(0, 0, 0); stageA(0, 0, 1); stageB(0, 0);
    stageA(1, 1, 0); stageA(1, 1, 1); stageB(1, 1);
    asm volatile("s_waitcnt vmcnt(6)" ::: "memory");
    __builtin_amdgcn_sched_barrier(0);
    __builtin_amdgcn_s_barrier();
    __builtin_amdgcn_sched_barrier(0);

#pragma unroll 1
    for (int t = 0; t < nt; ++t) {
      int cur = t % 3;
      int nxt = (t + 2) % 3;
      int kt2 = (t + 2 < nt) ? (t + 2) : t;
      const char* Ab = &lds[cur * 49152];
      const char* Bb = &lds[cur * 49152 + 32768];
      bf16x8 af[4][2], bfr[4][2];
#pragma unroll
      for (int mi = 0; mi < 4; ++mi) {
        int row = wm * 64 + mi * 16 + mr;
        const char* rb = Ab + row * 128;
        int sz = (row & 7) << 4;
        af[mi][0] = *(const bf16x8*)(rb + ((kg * 16) ^ sz));
        af[mi][1] = *(const bf16x8*)(rb + ((64 + kg * 16) ^ sz));
      }
#pragma unroll
      for (int ni = 0; ni < 4; ++ni) {
        int row = wn * 64 + ni * 16 + mr;
        const char* rb = Bb + row * 128;
        int sz = (row & 7) << 4;
        bfr[ni][0] = *(const bf16x8*)(rb + ((kg * 16) ^ sz));
        bfr[ni][1] = *(const bf16x8*)(rb + ((64 + kg * 16) ^ sz));
      }
      stageA(nxt, kt2, 0);
      __builtin_amdgcn_s_setprio(1);
#pragma unroll
      for (int mi = 0; mi < 4; ++mi) {
        acc[mi][0] = MFMA16(af[mi][0], bfr[0][0], acc[mi][0]);
        acc[mi][0] = MFMA16(af[mi][1], bfr[0][1], acc[mi][0]);
      }
      __builtin_amdgcn_s_setprio(0);
      stageA(nxt, kt2, 1);
      __builtin_amdgcn_s_setprio(1);
#pragma unroll
      for (int mi = 0; mi < 4; ++mi) {
        acc[mi][1] = MFMA16(af[mi][0], bfr[1][0], acc[mi][1]);
        acc[mi][1] = MFMA16(af[mi][1], bfr[1][1], acc[mi][1]);
      }
      __builtin_amdgcn_s_setprio(0);
      stageB(nxt, kt2);
      __builtin_amdgcn_s_setprio(1);
#pragma unroll
      for (int mi = 0; mi < 4; ++mi) {
        acc[mi][2] = MFMA16(af[mi][0], bfr[2][0], acc[mi][2]);
        acc[mi][2] = MFMA16(af[mi][1], bfr[2][1], acc[mi][2]);
        acc[mi][3] = MFMA16(af[mi][0], bfr[3][0], acc[mi][3]);
        acc[mi][3] = MFMA16(af[mi][1], bfr[3][1], acc[mi][3]);
      }
      __builtin_amdgcn_s_setprio(0);
      asm volatile("s_waitcnt vmcnt(6)" ::: "memory");
      __builtin_amdgcn_sched_barrier(0);
      __builtin_amdgcn_s_barrier();
      __builtin_amdgcn_sched_barrier(0);
    }
    asm volatile("s_waitcnt vmcnt(0)" ::: "memory");
    __syncthreads();

    // ---- v: transposed [d(128)][t(256)] epilogue ----
    char* tb = &lds[0];
    int h = (col0 >> 7) & 15;
    int b = row0 >> 11, t0 = row0 & 2047;
#pragma unroll
    for (int mi = 0; mi < 4; ++mi)
#pragma unroll
      for (int ni = 0; ni < 4; ++ni)
#pragma unroll
        for (int jj = 0; jj < 4; ++jj) {
          int rloc = wm * 64 + mi * 16 + kg * 4 + jj;
          int cloc = wn * 64 + ni * 16 + mr;
          *(bf16_t*)(tb + cloc * 512 + ((rloc * 2) ^ ((cloc & 7) << 4))) =
              (bf16_t)acc[mi][ni][jj];
        }
    __syncthreads();
    int d = tid >> 2, qt = tid & 3;
    const char* rowb = tb + d * 512;
    int sz = (d & 7) << 4;
    bf16_t* dst = vto + ((size_t)((b * 16 + h) * 128 + d)) * 2048 + t0 + qt * 64;
#pragma unroll
    for (int m2 = 0; m2 < 8; ++m2)
      *(bf16x8*)(dst + m2 * 8) = *(const bf16x8*)(rowb + ((qt * 128 + m2 * 16) ^ sz));
  }
}

// ------- GEMM 256x128 tile, BK=64, 512 thr, depth-2 (proj, MODE 0 only) -------
__global__ __launch_bounds__(512, 2) void gemm256(
    const bf16_t* __restrict__ A, const bf16_t* __restrict__ Bw, float* __restrict__ C,
    int M, int N, int K, int nby) {
  __shared__ __align__(16) char lds[147456];
  int tid = threadIdx.x;
  int w = tid >> 6, lane = tid & 63;
  int wm = w >> 1, wn = w & 1;
  int mr = lane & 15, kg = lane >> 4;

  int nwg = gridDim.x;
  int orig = blockIdx.x;
  int wgid = (orig & 7) * (nwg >> 3) + (orig >> 3);
  int by = wgid % nby, bx = wgid / nby;
  int row0 = by * 256, col0 = bx * 128;

  size_t aoff[4], boff[2];
#pragma unroll
  for (int it = 0; it < 4; ++it) {
    int c = tid + it * 512;
    int r = c >> 3;
    int chs = (c & 7) ^ (r & 7);
    aoff[it] = (size_t)(row0 + r) * K + chs * 8;
  }
#pragma unroll
  for (int it = 0; it < 2; ++it) {
    int c = tid + it * 512;
    int r = c >> 3;
    int chs = (c & 7) ^ (r & 7);
    boff[it] = (size_t)(col0 + r) * K + chs * 8;
  }

  auto stageA = [&](int buf, int kt, int half) {
    char* Ad = &lds[buf * 49152];
#pragma unroll
    for (int it = half * 2; it < half * 2 + 2; ++it)
      async_copy16(A + aoff[it] + kt * 64, Ad + (tid + it * 512) * 16);
  };
  auto stageB = [&](int buf, int kt) {
    char* Bd = &lds[buf * 49152 + 32768];
#pragma unroll
    for (int it = 0; it < 2; ++it)
      async_copy16(Bw + boff[it] + kt * 64, Bd + (tid + it * 512) * 16);
  };

  f32x4 zero = {0.f, 0.f, 0.f, 0.f};
  f32x4 acc[4][4];
#pragma unroll
  for (int mi = 0; mi < 4; ++mi)
#pragma unroll
    for (int ni = 0; ni < 4; ++ni) acc[mi][ni] = zero;

  int nt = K >> 6;
  stageA(0, 0, 0); stageA(0, 0, 1); stageB(0, 0);
  stageA(1, 1, 0); stageA(1, 1, 1); stageB(1, 1);
  asm volatile("s_waitcnt vmcnt(6)" ::: "memory");
  __builtin_amdgcn_sched_barrier(0);
  __builtin_amdgcn_s_barrier();
  __builtin_amdgcn_sched_barrier(0);

#pragma unroll 1
  for (int t = 0; t < nt; ++t) {
    int cur = t % 3;
    int nxt = (t + 2) % 3;
    int kt2 = (t + 2 < nt) ? (t + 2) : t;
    const char* Ab = &lds[cur * 49152];
    const char* Bb = &lds[cur * 49152 + 32768];
    bf16x8 af[4][2], bfr[4][2];
#pragma unroll
    for (int mi = 0; mi < 4; ++mi) {
      int row = wm * 64 + mi * 16 + mr;
      const char* rb = Ab + row * 128;
      int sz = (row & 7) << 4;
      af[mi][0] = *(const bf16x8*)(rb + ((kg * 16) ^ sz));
      af[mi][1] = *(const bf16x8*)(rb + ((64 + kg * 16) ^ sz));
    }
#pragma unroll
    for (int ni = 0; ni < 4; ++ni) {
      int row = wn * 64 + ni * 16 + mr;
      const char* rb = Bb + row * 128;
      int sz = (row & 7) << 4;
      bfr[ni][0] = *(const bf16x8*)(rb + ((kg * 16) ^ sz));
      bfr[ni][1] = *(const bf16x8*)(rb + ((64 + kg * 16) ^ sz));
    }
    stageA(nxt, kt2, 0);
    __builtin_amdgcn_s_setprio(1);
#pragma unroll
    for (int mi = 0; mi < 4; ++mi) {
      acc[mi][0] = MFMA16(af[mi][0], bfr[0][0], acc[mi][0]);
      acc[mi][0] = MFMA16(af[mi][1], bfr[0][1], acc[mi][0]);
    }
    __builtin_amdgcn_s_setprio(0);
    stageA(nxt, kt2, 1);
    __builtin_amdgcn_s_setprio(1);
#pragma unroll
    for (int mi = 0; mi < 4; ++mi) {
      acc[mi][1] = MFMA16(af[mi][0], bfr[1][0], acc[mi][1]);
      acc[mi][1] = MFMA16(af[mi][1], bfr[1][1], acc[mi][1]);
    }
    __builtin_amdgcn_s_setprio(0);
    stageB(nxt, kt2);
    __builtin_amdgcn_s_setprio(1);
#pragma unroll
    for (int mi = 0; mi < 4; ++mi) {
      acc[mi][2] = MFMA16(af[mi][0], bfr[2][0], acc[mi][2]);
      acc[mi][2] = MFMA16(af[mi][1], bfr[2][1], acc[mi][2]);
      acc[mi][3] = MFMA16(af[mi][0], bfr[3][0], acc[mi][3]);
      acc[mi][3] = MFMA16(af[mi][1], bfr[3][1], acc[mi][3]);
    }
    __builtin_amdgcn_s_setprio(0);
    asm volatile("s_waitcnt vmcnt(6)" ::: "memory");
    __builtin_amdgcn_sched_barrier(0);
    __builtin_amdgcn_s_barrier();
    __builtin_amdgcn_sched_barrier(0);
  }
  asm volatile("s_waitcnt vmcnt(0)" ::: "memory");
  __syncthreads();

#pragma unroll
  for (int mi = 0; mi < 4; ++mi)
#pragma unroll
    for (int ni = 0; ni < 4; ++ni)
#pragma unroll
      for (int jj = 0; jj < 4; ++jj) {
        int row = row0 + wm * 64 + mi * 16 + kg * 4 + jj;
        int col = col0 + wn * 64 + ni * 16 + mr;
        C[(size_t)row * N + col] = acc[mi][ni][jj];
      }
}

// ---------------- causal flash attention (v8, proven best) ----------------
__global__ __launch_bounds__(256, 2) void attn_kernel(
    const bf16_t* __restrict__ qg, const bf16_t* __restrict__ kgl,
    const bf16_t* __restrict__ vtg, bf16_t* __restrict__ og) {
  __shared__ __align__(16) bf16_t Ks[2][64 * 128];
  __shared__ __align__(16) bf16_t Vs[2][128 * 64];
  const int T = 2048;
  int tid = threadIdx.x;
  int w = tid >> 6, lane = tid & 63;
  int l31 = lane & 31, hi = lane >> 5;

  int L = blockIdx.x;
  int halfg = L >> 8;
  int Lr = L & 255;
  int role = (Lr & 7) * 32 + (Lr >> 3);
  int bx = role & 7, bh = role >> 3;
  int qb = halfg ? bx : (15 - bx);

  const bf16_t* Q = qg + (size_t)bh * T * 128;
  const bf16_t* K = kgl + (size_t)bh * T * 128;
  const bf16_t* Vt = vtg + (size_t)bh * 128 * T;

  int sb = tid * 16;
  int krl = sb >> 8;
  int kc = (sb & 255) ^ (krl << 4);
  size_t ksrc = (size_t)krl * 128 + (kc >> 1);
  int vdl = sb >> 7;
  int vc = (sb & 127) ^ ((vdl & 7) << 4);
  size_t vsrc = (size_t)vdl * 2048 + (vc >> 1);

  auto stage = [&](int buf, int kb) {
#pragma unroll
    for (int it = 0; it < 4; ++it)
      async_copy16(K + (size_t)(kb + it * 16) * 128 + ksrc, &Ks[buf][it * 2048 + tid * 8]);
#pragma unroll
    for (int it = 0; it < 4; ++it)
      async_copy16(Vt + (size_t)it * 65536 + kb + vsrc, &Vs[buf][it * 2048 + tid * 8]);
  };

  int b = bh >> 4, h = bh & 15;
  f32x16 zero16 = {0.f};
  int swzK = (l31 & 15) << 4;
  int swzV = (l31 & 7) << 4;

  int qw0 = qb * 128 + w * 32;
  int tq = qw0 + l31;
  const bf16_t* qrow = Q + (size_t)tq * 128 + hi * 8;
  bf16x8 qf[8];
#pragma unroll
  for (int dc = 0; dc < 8; ++dc) qf[dc] = *(const bf16x8*)(qrow + dc * 16);

  f32x16 acc[4];
#pragma unroll
  for (int dt = 0; dt < 4; ++dt) acc[dt] = zero16;
  float mrun = -1e30f, lpart = 0.f;

  int nj = 2 * qb + 2;
  stage(0, 0);
  stage(1, 64);
#pragma unroll 1
  for (int j = 0; j < nj; ++j) {
    int cur = j & 1;
    if (j + 1 < nj) {
      asm volatile("s_waitcnt vmcnt(8)" ::: "memory");
    } else {
      asm volatile("s_waitcnt vmcnt(0)" ::: "memory");
    }
    __builtin_amdgcn_sched_barrier(0);
    __syncthreads();
    int kb = j * 64;
    if (kb <= qw0) {
      const char* KsB = (const char*)&Ks[cur][0];
      const char* VsB = (const char*)&Vs[cur][0];
      f32x16 s0 = zero16, s1 = zero16;
      __builtin_amdgcn_s_setprio(1);
#pragma unroll
      for (int dc = 0; dc < 8; ++dc) {
        int cb = dc * 32 + hi * 16;
        bf16x8 k0 = *(const bf16x8*)(KsB + l31 * 256 + (cb ^ swzK));
        bf16x8 k1 = *(const bf16x8*)(KsB + (32 + l31) * 256 + (cb ^ swzK));
        s0 = MFMA32(k0, qf[dc], s0);
        s1 = MFMA32(k1, qf[dc], s1);
      }
      __builtin_amdgcn_s_setprio(0);
      float p0[16], p1[16];
      float lmax = -3e38f;
      bool diag = (kb + 63 > qw0);
#pragma unroll
      for (int r = 0; r < 16; ++r) {
        int kk = (r & 3) + 8 * (r >> 2) + 4 * hi;
        float v0 = s0[r], v1 = s1[r];
        if (diag) {
          if (kb + kk > tq) v0 = -1e30f;
          if (kb + 32 + kk > tq) v1 = -1e30f;
        }
        p0[r] = v0; p1[r] = v1;
        lmax = fmaxf(lmax, fmaxf(v0, v1));
      }
      bool ok = (lmax <= mrun + 8.0f);
      if (!__all(ok)) {
        float tmax = fmaxf(lmax, __shfl_xor(lmax, 32, 64));
        float mn = fmaxf(mrun, tmax);
        float corr = __builtin_amdgcn_exp2f(mrun - mn);
        mrun = mn;
        lpart *= corr;
#pragma unroll
        for (int dt = 0; dt < 4; ++dt)
#pragma unroll
          for (int r = 0; r < 16; ++r) acc[dt][r] *= corr;
      }
#pragma unroll
      for (int r = 0; r < 16; ++r) {
        float e0 = __builtin_amdgcn_exp2f(p0[r] - mrun);
        float e1 = __builtin_amdgcn_exp2f(p1[r] - mrun);
        p0[r] = e0; p1[r] = e1;
        lpart += e0 + e1;
      }
      bf16x8 pa0, pa1, pa2, pa3;
#define BUILD_PA(dst, P, B0)                                         \
      { unsigned a0 = cvtpk(P[(B0) + 0], P[(B0) + 1]);               \
        unsigned a1 = cvtpk(P[(B0) + 2], P[(B0) + 3]);               \
        unsigned b0 = cvtpk(P[(B0) + 4], P[(B0) + 5]);               \
        unsigned b1 = cvtpk(P[(B0) + 6], P[(B0) + 7]);               \
        unsigned xa0 = __shfl_xor(a0, 32, 64);                       \
        unsigned xa1 = __shfl_xor(a1, 32, 64);                       \
        unsigned xb0 = __shfl_xor(b0, 32, 64);                       \
        unsigned xb1 = __shfl_xor(b1, 32, 64);                       \
        u32x4v fw;                                                   \
        fw[0] = hi ? xb0 : a0; fw[1] = hi ? xb1 : a1;                \
        fw[2] = hi ? b0 : xa0; fw[3] = hi ? b1 : xa1;                \
        dst = __builtin_bit_cast(bf16x8, fw); }
      BUILD_PA(pa0, p0, 0)
      BUILD_PA(pa1, p0, 8)
      BUILD_PA(pa2, p1, 0)
      BUILD_PA(pa3, p1, 8)
#undef BUILD_PA
      __builtin_amdgcn_s_setprio(1);
#pragma unroll
      for (int dt = 0; dt < 4; ++dt) {
        const char* vrow = VsB + (dt * 32 + l31) * 128;
        bf16x8 v0 = *(const bf16x8*)(vrow + ((hi * 16) ^ swzV));
        bf16x8 v1 = *(const bf16x8*)(vrow + ((32 + hi * 16) ^ swzV));
        bf16x8 v2 = *(const bf16x8*)(vrow + ((64 + hi * 16) ^ swzV));
        bf16x8 v3 = *(const bf16x8*)(vrow + ((96 + hi * 16) ^ swzV));
        acc[dt] = MFMA32(v0, pa0, acc[dt]);
        acc[dt] = MFMA32(v1, pa1, acc[dt]);
        acc[dt] = MFMA32(v2, pa2, acc[dt]);
        acc[dt] = MFMA32(v3, pa3, acc[dt]);
      }
      __builtin_amdgcn_s_setprio(0);
    }
    __syncthreads();
    if (j + 2 < nj) stage(cur, (j + 2) * 64);
  }
  float l = lpart + __shfl_xor(lpart, 32, 64);
  float invl = 1.0f / l;
  size_t orow_idx = (size_t)b * 2048 + h * 128 + (tq >> 4);
  bf16_t* orow = og + orow_idx * 2048 + (tq & 15) * 128;
#pragma unroll
  for (int dt = 0; dt < 4; ++dt)
#pragma unroll
    for (int g = 0; g < 4; ++g) {
      bf16x4 v4;
#pragma unroll
      for (int e = 0; e < 4; ++e) v4[e] = (bf16_t)(acc[dt][4 * g + e] * invl);
      *(bf16x4*)(orow + dt * 32 + 8 * g + 4 * hi) = v4;
    }
}

extern "C" void kernel_launch(void* const* d_in, const int* in_sizes, int n_in,
                              void* d_out, int out_size, void* d_ws, size_t ws_size,
                              hipStream_t stream) {
  const float* x = (const float*)d_in[0];      // [2,2048,2048]
  const float* wqkv = (const float*)d_in[1];   // [6144,2048]
  const float* wproj = (const float*)d_in[2];  // [2048,2048]
  float* out = (float*)d_out;                  // [2,2048,2048]
  char* ws = (char*)d_ws;

  const size_t OFF_WQKV = 16777216;
  const size_t OFF_WPROJ = 41943040;
  const size_t OFF_Q = 50331648;
  const size_t OFF_K = 67108864;
  const size_t OFF_VT = 83886080;

  bf16_t* xb = (bf16_t*)(ws);
  bf16_t* wqkvb = (bf16_t*)(ws + OFF_WQKV);
  bf16_t* wprojb = (bf16_t*)(ws + OFF_WPROJ);
  bf16_t* g_q = (bf16_t*)(ws + OFF_Q);
  bf16_t* g_k = (bf16_t*)(ws + OFF_K);
  bf16_t* g_vt = (bf16_t*)(ws + OFF_VT);
  bf16_t* g_att = (bf16_t*)(ws);               // alias xb (dead after gemms)

  cast_all<<<4096, 256, 0, stream>>>(x, wqkv, wproj, xb, wqkvb, wprojb);
  // fused QKV: 512 blocks (256 qk + 256 v) in one dispatch
  gemm_fused<<<512, 512, 0, stream>>>(xb, wqkvb, g_q, g_k, g_vt, 2048);
  // attn v8: 512 blocks (heavy half + light half)
  attn_kernel<<<512, 256, 0, stream>>>(g_q, g_k, g_vt, g_att);
  // output projection
  gemm256<<<256, 512, 0, stream>>>(g_att, wprojb, out, 4096, 2048, 2048, 16);
}

// Round 20
// 243.366 us; speedup vs baseline: 1.0128x; 1.0128x over previous
//
#include <hip/hip_runtime.h>
#include <hip/hip_bf16.h>

typedef __bf16 bf16_t;
typedef __bf16 bf16x8 __attribute__((ext_vector_type(8)));
typedef __bf16 bf16x4 __attribute__((ext_vector_type(4)));
typedef float f32x4 __attribute__((ext_vector_type(4)));
typedef float f32x16 __attribute__((ext_vector_type(16)));
typedef unsigned u32x4v __attribute__((ext_vector_type(4)));

#define MFMA16(a, b, c) __builtin_amdgcn_mfma_f32_16x16x32_bf16(a, b, c, 0, 0, 0)
#define MFMA32(a, b, c) __builtin_amdgcn_mfma_f32_32x32x16_bf16(a, b, c, 0, 0, 0)

__device__ __forceinline__ void async_copy16(const void* g, void* l) {
  __builtin_amdgcn_global_load_lds(
      (const __attribute__((address_space(1))) void*)g,
      (__attribute__((address_space(3))) void*)l, 16, 0, 0);
}

__device__ __forceinline__ unsigned cvtpk(float lo, float hi) {
  unsigned r;
  asm("v_cvt_pk_bf16_f32 %0, %1, %2" : "=v"(r) : "v"(lo), "v"(hi));
  return r;
}

// ---------------- fused cast f32 -> bf16 for all three inputs ----------------
__global__ void cast_all(const float* __restrict__ x, const float* __restrict__ wqkv,
                         const float* __restrict__ wproj, bf16_t* __restrict__ xb,
                         bf16_t* __restrict__ wqkvb, bf16_t* __restrict__ wprojb) {
  int stride = gridDim.x * blockDim.x;
  for (int i = blockIdx.x * blockDim.x + threadIdx.x; i < 3145728; i += stride) {
    const float* src;
    bf16_t* dst;
    int idx;
    if (i < 1048576) { src = x; dst = xb; idx = i; }
    else if (i < 2621440) { src = wqkv; dst = wqkvb; idx = i - 1048576; }
    else { src = wproj; dst = wprojb; idx = i - 2621440; }
    const float* p = src + (size_t)idx * 8;
    f32x4 a = *(const f32x4*)p;
    f32x4 b = *(const f32x4*)(p + 4);
    bf16x8 o;
    o[0] = (bf16_t)a[0]; o[1] = (bf16_t)a[1]; o[2] = (bf16_t)a[2]; o[3] = (bf16_t)a[3];
    o[4] = (bf16_t)b[0]; o[5] = (bf16_t)b[1]; o[6] = (bf16_t)b[2]; o[7] = (bf16_t)b[3];
    *(bf16x8*)(dst + (size_t)idx * 8) = o;
  }
}

// ======== GEMM-QK: 256x256, BK=64, 512thr (8 waves 2Mx4N), 4-phase ========
__global__ __launch_bounds__(512, 2) void gemm_qkv(
    const bf16_t* __restrict__ A, const bf16_t* __restrict__ Bw,
    bf16_t* __restrict__ qo, bf16_t* __restrict__ ko,
    int K) {
  __shared__ __align__(16) char lds[131072];
  int tid = threadIdx.x;
  int w = tid >> 6, lane = tid & 63;
  int wm = w & 1, wn = w >> 1;
  int mr = lane & 15, kg = lane >> 4;

  int orig = blockIdx.x;
  int chunk = orig & 7, i = orig >> 3;
  int by = (chunk & 3) * 4 + (i & 3);
  int bx = (chunk >> 2) * 8 + (i >> 2);
  int row0 = by * 256, col0 = bx * 256;

  int lr = tid >> 3, ch = (tid & 7) ^ (lr & 7);
  size_t aoff[4], boff[4];
#pragma unroll
  for (int g = 0; g < 4; ++g) {
    int gr = g * 32 + (lr & 31) + (lr >> 5) * 128;
    aoff[g] = (size_t)(row0 + gr) * K + ch * 8;
  }
#pragma unroll
  for (int p = 0; p < 4; ++p) {
    int gr = (lr >> 4) * 64 + p * 16 + (lr & 15);
    boff[p] = (size_t)(col0 + gr) * K + ch * 8;
  }

  auto stgA = [&](int q, int g, int kt) {
    async_copy16(A + aoff[g] + kt * 64, lds + q * 65536 + g * 8192 + tid * 16);
  };
  auto stgB = [&](int q, int p, int kt) {
    async_copy16(Bw + boff[p] + kt * 64, lds + q * 65536 + 32768 + p * 8192 + tid * 16);
  };

  f32x4 zero = {0.f, 0.f, 0.f, 0.f};
  f32x4 acc[8][4];
#pragma unroll
  for (int mi = 0; mi < 8; ++mi)
#pragma unroll
    for (int ni = 0; ni < 4; ++ni) acc[mi][ni] = zero;

  int nt = K >> 6;  // 32

  stgB(0, 0, 0); stgB(0, 1, 0); stgB(0, 2, 0); stgB(0, 3, 0);
  stgA(0, 0, 0); stgA(0, 1, 0); stgA(0, 2, 0); stgA(0, 3, 0);
  asm volatile("s_waitcnt vmcnt(0)" ::: "memory");
  __builtin_amdgcn_sched_barrier(0);
  __builtin_amdgcn_s_barrier();
  __builtin_amdgcn_sched_barrier(0);

#pragma unroll 1
  for (int t = 0; t < nt; ++t) {
    int q = t & 1, qn = q ^ 1;
    int kt = (t + 1 < nt) ? (t + 1) : t;
    const char* Ab = lds + q * 65536;
    const char* Bb = Ab + 32768;
    bf16x8 bf[4][2];

#define QKV_PHASE(MI0, STG, DOWAIT)                                             \
    {                                                                           \
      int r0 = ((MI0) >> 1) * 64 + wm * 32 + mr;                                \
      int r1 = r0 + 16;                                                         \
      bf16x8 a00 = *(const bf16x8*)(Ab + r0 * 128 + ((kg * 16) ^ ((r0 & 7) << 4)));      \
      bf16x8 a01 = *(const bf16x8*)(Ab + r0 * 128 + ((64 + kg * 16) ^ ((r0 & 7) << 4))); \
      bf16x8 a10 = *(const bf16x8*)(Ab + r1 * 128 + ((kg * 16) ^ ((r1 & 7) << 4)));      \
      bf16x8 a11 = *(const bf16x8*)(Ab + r1 * 128 + ((64 + kg * 16) ^ ((r1 & 7) << 4))); \
      STG;                                                                      \
      __builtin_amdgcn_sched_barrier(0);                                        \
      if (DOWAIT) { asm volatile("s_waitcnt vmcnt(4)" ::: "memory"); }          \
      __builtin_amdgcn_s_barrier();                                             \
      asm volatile("s_waitcnt lgkmcnt(0)" ::: "memory");                        \
      __builtin_amdgcn_sched_barrier(0);                                        \
      __builtin_amdgcn_s_setprio(1);                                            \
      _Pragma("unroll")                                                         \
      for (int ni = 0; ni < 4; ++ni) {                                          \
        acc[MI0][ni] = MFMA16(a00, bf[ni][0], acc[MI0][ni]);                    \
        acc[MI0][ni] = MFMA16(a01, bf[ni][1], acc[MI0][ni]);                    \
        acc[(MI0) + 1][ni] = MFMA16(a10, bf[ni][0], acc[(MI0) + 1][ni]);        \
        acc[(MI0) + 1][ni] = MFMA16(a11, bf[ni][1], acc[(MI0) + 1][ni]);        \
      }                                                                         \
      __builtin_amdgcn_s_setprio(0);                                            \
      __builtin_amdgcn_sched_barrier(0);                                        \
      __builtin_amdgcn_s_barrier();                                             \
      __builtin_amdgcn_sched_barrier(0);                                        \
    }

#pragma unroll
    for (int ni = 0; ni < 4; ++ni) {
      int rb = ni * 64 + wn * 16 + mr;
      bf[ni][0] = *(const bf16x8*)(Bb + rb * 128 + ((kg * 16) ^ ((rb & 7) << 4)));
      bf[ni][1] = *(const bf16x8*)(Bb + rb * 128 + ((64 + kg * 16) ^ ((rb & 7) << 4)));
    }
    QKV_PHASE(0, (stgA(qn, 0, kt), stgA(qn, 1, kt), stgB(qn, 0, kt), stgB(qn, 1, kt)), 1)
    QKV_PHASE(2, (stgA(qn, 2, kt), stgA(qn, 3, kt), stgB(qn, 2, kt), stgB(qn, 3, kt)), 0)
    QKV_PHASE(4, (void)0, 0)
    QKV_PHASE(6, (void)0, 0)
#undef QKV_PHASE
  }
  asm volatile("s_waitcnt vmcnt(0)" ::: "memory");
  __syncthreads();

  // ---- fused RoPE epilogue (q pre-scaled) ----
  char* tb = &lds[0];
  int s = col0 >> 11;
  int h0 = (col0 >> 7) & 15;
  int b = row0 >> 11, t0 = row0 & 2047;
#pragma unroll
  for (int mi = 0; mi < 8; ++mi)
#pragma unroll
    for (int ni = 0; ni < 4; ++ni)
#pragma unroll
      for (int jj = 0; jj < 4; ++jj) {
        int rl = wm * 128 + mi * 16 + kg * 4 + jj;
        int cb = (wn * 64 + ni * 16 + mr) * 2;
        *(bf16_t*)(tb + rl * 512 + (cb ^ ((rl & 7) << 4))) = (bf16_t)acc[mi][ni][jj];
      }
  __syncthreads();
  int r = tid >> 1, hs = tid & 1;
  const char* rowb = tb + r * 512;
  int sz = (r & 7) << 4;
  int t = t0 + r;
  bf16_t* dst = (s == 0 ? qo : ko) + ((size_t)((b * 16 + h0 + hs) * 2048 + t)) * 128;
  float tf = (float)t;
  const float cinv = -0.20762050593046014f;  // -log2(10000)/64
  float postm = (s == 0) ? 0.12751744f : 1.0f;
  bf16x8 vin[16];
#pragma unroll
  for (int m = 0; m < 16; ++m)
    vin[m] = *(const bf16x8*)(rowb + ((hs * 256 + m * 16) ^ sz));
#pragma unroll
  for (int m = 0; m < 8; ++m) {
    bf16x8 o1, o2;
#pragma unroll
    for (int e = 0; e < 8; ++e) {
      float ang = tf * exp2f((float)(m * 8 + e) * cinv);
      float sv = __sinf(ang), cv = __cosf(ang);
      float x1 = (float)vin[m][e], x2 = (float)vin[m + 8][e];
      o1[e] = (bf16_t)((x1 * cv - x2 * sv) * postm);
      o2[e] = (bf16_t)((x2 * cv + x1 * sv) * postm);
    }
    *(bf16x8*)(dst + m * 8) = o1;
    *(bf16x8*)(dst + 64 + m * 8) = o2;
  }
}

// ------- GEMM 256x128 tile, BK=64, 512 thr, depth-2 (R6 proven body) -------
template <int MODE>
__global__ __launch_bounds__(512, 2) void gemm256(
    const bf16_t* __restrict__ A, const bf16_t* __restrict__ Bw, float* __restrict__ C,
    bf16_t* __restrict__ vto, int M, int N, int K, int nby, int colbase) {
  __shared__ __align__(16) char lds[147456];
  int tid = threadIdx.x;
  int w = tid >> 6, lane = tid & 63;
  int wm = w >> 1, wn = w & 1;
  int mr = lane & 15, kg = lane >> 4;

  int nwg = gridDim.x;
  int orig = blockIdx.x;
  int wgid = (orig & 7) * (nwg >> 3) + (orig >> 3);
  int by = wgid % nby, bx = wgid / nby;
  int row0 = by * 256, col0 = colbase + bx * 128;

  size_t aoff[4], boff[2];
#pragma unroll
  for (int it = 0; it < 4; ++it) {
    int c = tid + it * 512;
    int r = c >> 3;
    int chs = (c & 7) ^ (r & 7);
    aoff[it] = (size_t)(row0 + r) * K + chs * 8;
  }
#pragma unroll
  for (int it = 0; it < 2; ++it) {
    int c = tid + it * 512;
    int r = c >> 3;
    int chs = (c & 7) ^ (r & 7);
    boff[it] = (size_t)(col0 - colbase + r) * K + chs * 8;
  }

  auto stageA = [&](int buf, int kt, int half) {
    char* Ad = &lds[buf * 49152];
#pragma unroll
    for (int it = half * 2; it < half * 2 + 2; ++it)
      async_copy16(A + aoff[it] + kt * 64, Ad + (tid + it * 512) * 16);
  };
  auto stageB = [&](int buf, int kt) {
    char* Bd = &lds[buf * 49152 + 32768];
#pragma unroll
    for (int it = 0; it < 2; ++it)
      async_copy16(Bw + boff[it] + kt * 64, Bd + (tid + it * 512) * 16);
  };

  f32x4 zero = {0.f, 0.f, 0.f, 0.f};
  f32x4 acc[4][4];
#pragma unroll
  for (int mi = 0; mi < 4; ++mi)
#pragma unroll
    for (int ni = 0; ni < 4; ++ni) acc[mi][ni] = zero;

  int nt = K >> 6;
  stageA(0, 0, 0); stageA(0, 0, 1); stageB(0, 0);
  stageA(1, 1, 0); stageA(1, 1, 1); stageB(1, 1);
  asm volatile("s_waitcnt vmcnt(6)" ::: "memory");
  __builtin_amdgcn_sched_barrier(0);
  __builtin_amdgcn_s_barrier();
  __builtin_amdgcn_sched_barrier(0);

#pragma unroll 1
  for (int t = 0; t < nt; ++t) {
    int cur = t % 3;
    int nxt = (t + 2) % 3;
    int kt2 = (t + 2 < nt) ? (t + 2) : t;
    const char* Ab = &lds[cur * 49152];
    const char* Bb = &lds[cur * 49152 + 32768];
    bf16x8 af[4][2], bfr[4][2];
#pragma unroll
    for (int mi = 0; mi < 4; ++mi) {
      int row = wm * 64 + mi * 16 + mr;
      const char* rb = Ab + row * 128;
      int sz = (row & 7) << 4;
      af[mi][0] = *(const bf16x8*)(rb + ((kg * 16) ^ sz));
      af[mi][1] = *(const bf16x8*)(rb + ((64 + kg * 16) ^ sz));
    }
#pragma unroll
    for (int ni = 0; ni < 4; ++ni) {
      int row = wn * 64 + ni * 16 + mr;
      const char* rb = Bb + row * 128;
      int sz = (row & 7) << 4;
      bfr[ni][0] = *(const bf16x8*)(rb + ((kg * 16) ^ sz));
      bfr[ni][1] = *(const bf16x8*)(rb + ((64 + kg * 16) ^ sz));
    }
    stageA(nxt, kt2, 0);
    __builtin_amdgcn_s_setprio(1);
#pragma unroll
    for (int mi = 0; mi < 4; ++mi) {
      acc[mi][0] = MFMA16(af[mi][0], bfr[0][0], acc[mi][0]);
      acc[mi][0] = MFMA16(af[mi][1], bfr[0][1], acc[mi][0]);
    }
    __builtin_amdgcn_s_setprio(0);
    stageA(nxt, kt2, 1);
    __builtin_amdgcn_s_setprio(1);
#pragma unroll
    for (int mi = 0; mi < 4; ++mi) {
      acc[mi][1] = MFMA16(af[mi][0], bfr[1][0], acc[mi][1]);
      acc[mi][1] = MFMA16(af[mi][1], bfr[1][1], acc[mi][1]);
    }
    __builtin_amdgcn_s_setprio(0);
    stageB(nxt, kt2);
    __builtin_amdgcn_s_setprio(1);
#pragma unroll
    for (int mi = 0; mi < 4; ++mi) {
      acc[mi][2] = MFMA16(af[mi][0], bfr[2][0], acc[mi][2]);
      acc[mi][2] = MFMA16(af[mi][1], bfr[2][1], acc[mi][2]);
      acc[mi][3] = MFMA16(af[mi][0], bfr[3][0], acc[mi][3]);
      acc[mi][3] = MFMA16(af[mi][1], bfr[3][1], acc[mi][3]);
    }
    __builtin_amdgcn_s_setprio(0);
    asm volatile("s_waitcnt vmcnt(6)" ::: "memory");
    __builtin_amdgcn_sched_barrier(0);
    __builtin_amdgcn_s_barrier();
    __builtin_amdgcn_sched_barrier(0);
  }
  asm volatile("s_waitcnt vmcnt(0)" ::: "memory");
  __syncthreads();

  if (MODE == 0) {
#pragma unroll
    for (int mi = 0; mi < 4; ++mi)
#pragma unroll
      for (int ni = 0; ni < 4; ++ni)
#pragma unroll
        for (int jj = 0; jj < 4; ++jj) {
          int row = row0 + wm * 64 + mi * 16 + kg * 4 + jj;
          int col = col0 + wn * 64 + ni * 16 + mr;
          C[(size_t)row * N + col] = acc[mi][ni][jj];
        }
  } else {
    char* tb = &lds[0];
    int h = (col0 >> 7) & 15;
    int b = row0 >> 11, t0 = row0 & 2047;
#pragma unroll
    for (int mi = 0; mi < 4; ++mi)
#pragma unroll
      for (int ni = 0; ni < 4; ++ni)
#pragma unroll
        for (int jj = 0; jj < 4; ++jj) {
          int rloc = wm * 64 + mi * 16 + kg * 4 + jj;
          int cloc = wn * 64 + ni * 16 + mr;
          *(bf16_t*)(tb + cloc * 512 + ((rloc * 2) ^ ((cloc & 7) << 4))) =
              (bf16_t)acc[mi][ni][jj];
        }
    __syncthreads();
    int d = tid >> 2, qt = tid & 3;
    const char* rowb = tb + d * 512;
    int sz = (d & 7) << 4;
    bf16_t* dst = vto + ((size_t)((b * 16 + h) * 128 + d)) * 2048 + t0 + qt * 64;
#pragma unroll
    for (int m2 = 0; m2 < 8; ++m2)
      *(bf16x8*)(dst + m2 * 8) = *(const bf16x8*)(rowb + ((qt * 128 + m2 * 16) ^ sz));
  }
}

// ---------------- causal flash attention (v8, proven best) ----------------
__global__ __launch_bounds__(256, 2) void attn_kernel(
    const bf16_t* __restrict__ qg, const bf16_t* __restrict__ kgl,
    const bf16_t* __restrict__ vtg, bf16_t* __restrict__ og) {
  __shared__ __align__(16) bf16_t Ks[2][64 * 128];
  __shared__ __align__(16) bf16_t Vs[2][128 * 64];
  const int T = 2048;
  int tid = threadIdx.x;
  int w = tid >> 6, lane = tid & 63;
  int l31 = lane & 31, hi = lane >> 5;

  int L = blockIdx.x;
  int halfg = L >> 8;
  int Lr = L & 255;
  int role = (Lr & 7) * 32 + (Lr >> 3);
  int bx = role & 7, bh = role >> 3;
  int qb = halfg ? bx : (15 - bx);

  const bf16_t* Q = qg + (size_t)bh * T * 128;
  const bf16_t* K = kgl + (size_t)bh * T * 128;
  const bf16_t* Vt = vtg + (size_t)bh * 128 * T;

  int sb = tid * 16;
  int krl = sb >> 8;
  int kc = (sb & 255) ^ (krl << 4);
  size_t ksrc = (size_t)krl * 128 + (kc >> 1);
  int vdl = sb >> 7;
  int vc = (sb & 127) ^ ((vdl & 7) << 4);
  size_t vsrc = (size_t)vdl * 2048 + (vc >> 1);

  auto stage = [&](int buf, int kb) {
#pragma unroll
    for (int it = 0; it < 4; ++it)
      async_copy16(K + (size_t)(kb + it * 16) * 128 + ksrc, &Ks[buf][it * 2048 + tid * 8]);
#pragma unroll
    for (int it = 0; it < 4; ++it)
      async_copy16(Vt + (size_t)it * 65536 + kb + vsrc, &Vs[buf][it * 2048 + tid * 8]);
  };

  int b = bh >> 4, h = bh & 15;
  f32x16 zero16 = {0.f};
  int swzK = (l31 & 15) << 4;
  int swzV = (l31 & 7) << 4;

  int qw0 = qb * 128 + w * 32;
  int tq = qw0 + l31;
  const bf16_t* qrow = Q + (size_t)tq * 128 + hi * 8;
  bf16x8 qf[8];
#pragma unroll
  for (int dc = 0; dc < 8; ++dc) qf[dc] = *(const bf16x8*)(qrow + dc * 16);

  f32x16 acc[4];
#pragma unroll
  for (int dt = 0; dt < 4; ++dt) acc[dt] = zero16;
  float mrun = -1e30f, lpart = 0.f;

  int nj = 2 * qb + 2;
  stage(0, 0);
  stage(1, 64);
#pragma unroll 1
  for (int j = 0; j < nj; ++j) {
    int cur = j & 1;
    if (j + 1 < nj) {
      asm volatile("s_waitcnt vmcnt(8)" ::: "memory");
    } else {
      asm volatile("s_waitcnt vmcnt(0)" ::: "memory");
    }
    __builtin_amdgcn_sched_barrier(0);
    __syncthreads();
    int kb = j * 64;
    if (kb <= qw0) {
      const char* KsB = (const char*)&Ks[cur][0];
      const char* VsB = (const char*)&Vs[cur][0];
      f32x16 s0 = zero16, s1 = zero16;
      __builtin_amdgcn_s_setprio(1);
#pragma unroll
      for (int dc = 0; dc < 8; ++dc) {
        int cb = dc * 32 + hi * 16;
        bf16x8 k0 = *(const bf16x8*)(KsB + l31 * 256 + (cb ^ swzK));
        bf16x8 k1 = *(const bf16x8*)(KsB + (32 + l31) * 256 + (cb ^ swzK));
        s0 = MFMA32(k0, qf[dc], s0);
        s1 = MFMA32(k1, qf[dc], s1);
      }
      __builtin_amdgcn_s_setprio(0);
      float p0[16], p1[16];
      float lmax = -3e38f;
      bool diag = (kb + 63 > qw0);
#pragma unroll
      for (int r = 0; r < 16; ++r) {
        int kk = (r & 3) + 8 * (r >> 2) + 4 * hi;
        float v0 = s0[r], v1 = s1[r];
        if (diag) {
          if (kb + kk > tq) v0 = -1e30f;
          if (kb + 32 + kk > tq) v1 = -1e30f;
        }
        p0[r] = v0; p1[r] = v1;
        lmax = fmaxf(lmax, fmaxf(v0, v1));
      }
      bool ok = (lmax <= mrun + 8.0f);
      if (!__all(ok)) {
        float tmax = fmaxf(lmax, __shfl_xor(lmax, 32, 64));
        float mn = fmaxf(mrun, tmax);
        float corr = __builtin_amdgcn_exp2f(mrun - mn);
        mrun = mn;
        lpart *= corr;
#pragma unroll
        for (int dt = 0; dt < 4; ++dt)
#pragma unroll
          for (int r = 0; r < 16; ++r) acc[dt][r] *= corr;
      }
#pragma unroll
      for (int r = 0; r < 16; ++r) {
        float e0 = __builtin_amdgcn_exp2f(p0[r] - mrun);
        float e1 = __builtin_amdgcn_exp2f(p1[r] - mrun);
        p0[r] = e0; p1[r] = e1;
        lpart += e0 + e1;
      }
      bf16x8 pa0, pa1, pa2, pa3;
#define BUILD_PA(dst, P, B0)                                         \
      { unsigned a0 = cvtpk(P[(B0) + 0], P[(B0) + 1]);               \
        unsigned a1 = cvtpk(P[(B0) + 2], P[(B0) + 3]);               \
        unsigned b0 = cvtpk(P[(B0) + 4], P[(B0) + 5]);               \
        unsigned b1 = cvtpk(P[(B0) + 6], P[(B0) + 7]);               \
        unsigned xa0 = __shfl_xor(a0, 32, 64);                       \
        unsigned xa1 = __shfl_xor(a1, 32, 64);                       \
        unsigned xb0 = __shfl_xor(b0, 32, 64);                       \
        unsigned xb1 = __shfl_xor(b1, 32, 64);                       \
        u32x4v fw;                                                   \
        fw[0] = hi ? xb0 : a0; fw[1] = hi ? xb1 : a1;                \
        fw[2] = hi ? b0 : xa0; fw[3] = hi ? b1 : xa1;                \
        dst = __builtin_bit_cast(bf16x8, fw); }
      BUILD_PA(pa0, p0, 0)
      BUILD_PA(pa1, p0, 8)
      BUILD_PA(pa2, p1, 0)
      BUILD_PA(pa3, p1, 8)
#undef BUILD_PA
      __builtin_amdgcn_s_setprio(1);
#pragma unroll
      for (int dt = 0; dt < 4; ++dt) {
        const char* vrow = VsB + (dt * 32 + l31) * 128;
        bf16x8 v0 = *(const bf16x8*)(vrow + ((hi * 16) ^ swzV));
        bf16x8 v1 = *(const bf16x8*)(vrow + ((32 + hi * 16) ^ swzV));
        bf16x8 v2 = *(const bf16x8*)(vrow + ((64 + hi * 16) ^ swzV));
        bf16x8 v3 = *(const bf16x8*)(vrow + ((96 + hi * 16) ^ swzV));
        acc[dt] = MFMA32(v0, pa0, acc[dt]);
        acc[dt] = MFMA32(v1, pa1, acc[dt]);
        acc[dt] = MFMA32(v2, pa2, acc[dt]);
        acc[dt] = MFMA32(v3, pa3, acc[dt]);
      }
      __builtin_amdgcn_s_setprio(0);
    }
    __syncthreads();
    if (j + 2 < nj) stage(cur, (j + 2) * 64);
  }
  float l = lpart + __shfl_xor(lpart, 32, 64);
  float invl = 1.0f / l;
  size_t orow_idx = (size_t)b * 2048 + h * 128 + (tq >> 4);
  bf16_t* orow = og + orow_idx * 2048 + (tq & 15) * 128;
#pragma unroll
  for (int dt = 0; dt < 4; ++dt)
#pragma unroll
    for (int g = 0; g < 4; ++g) {
      bf16x4 v4;
#pragma unroll
      for (int e = 0; e < 4; ++e) v4[e] = (bf16_t)(acc[dt][4 * g + e] * invl);
      *(bf16x4*)(orow + dt * 32 + 8 * g + 4 * hi) = v4;
    }
}

extern "C" void kernel_launch(void* const* d_in, const int* in_sizes, int n_in,
                              void* d_out, int out_size, void* d_ws, size_t ws_size,
                              hipStream_t stream) {
  const float* x = (const float*)d_in[0];      // [2,2048,2048]
  const float* wqkv = (const float*)d_in[1];   // [6144,2048]
  const float* wproj = (const float*)d_in[2];  // [2048,2048]
  float* out = (float*)d_out;                  // [2,2048,2048]
  char* ws = (char*)d_ws;

  const size_t OFF_WQKV = 16777216;
  const size_t OFF_WPROJ = 41943040;
  const size_t OFF_Q = 50331648;
  const size_t OFF_K = 67108864;
  const size_t OFF_VT = 83886080;

  bf16_t* xb = (bf16_t*)(ws);
  bf16_t* wqkvb = (bf16_t*)(ws + OFF_WQKV);
  bf16_t* wprojb = (bf16_t*)(ws + OFF_WPROJ);
  bf16_t* g_q = (bf16_t*)(ws + OFF_Q);
  bf16_t* g_k = (bf16_t*)(ws + OFF_K);
  bf16_t* g_vt = (bf16_t*)(ws + OFF_VT);
  bf16_t* g_att = (bf16_t*)(ws);               // alias xb (dead after gemms)

  cast_all<<<4096, 256, 0, stream>>>(x, wqkv, wproj, xb, wqkvb, wprojb);
  gemm_qkv<<<256, 512, 0, stream>>>(xb, wqkvb, g_q, g_k, 2048);
  gemm256<1><<<256, 512, 0, stream>>>(xb, wqkvb + (size_t)4096 * 2048, nullptr, g_vt,
                                      4096, 2048, 2048, 16, 4096);
  // attn v8: 512 blocks (heavy half + light half), 2 blocks/CU — best measured
  attn_kernel<<<512, 256, 0, stream>>>(g_q, g_k, g_vt, g_att);
  gemm256<0><<<256, 512, 0, stream>>>(g_att, wprojb, out, nullptr, 4096, 2048, 2048, 16, 0);
}

// Round 21
// 242.434 us; speedup vs baseline: 1.0167x; 1.0038x over previous
//
#include <hip/hip_runtime.h>
#include <hip/hip_bf16.h>

typedef __bf16 bf16_t;
typedef __bf16 bf16x8 __attribute__((ext_vector_type(8)));
typedef __bf16 bf16x4 __attribute__((ext_vector_type(4)));
typedef float f32x4 __attribute__((ext_vector_type(4)));
typedef float f32x16 __attribute__((ext_vector_type(16)));
typedef unsigned u32x4v __attribute__((ext_vector_type(4)));

#define MFMA16(a, b, c) __builtin_amdgcn_mfma_f32_16x16x32_bf16(a, b, c, 0, 0, 0)
#define MFMA32(a, b, c) __builtin_amdgcn_mfma_f32_32x32x16_bf16(a, b, c, 0, 0, 0)

__device__ __forceinline__ void async_copy16(const void* g, void* l) {
  __builtin_amdgcn_global_load_lds(
      (const __attribute__((address_space(1))) void*)g,
      (__attribute__((address_space(3))) void*)l, 16, 0, 0);
}

__device__ __forceinline__ unsigned cvtpk(float lo, float hi) {
  unsigned r;
  asm("v_cvt_pk_bf16_f32 %0, %1, %2" : "=v"(r) : "v"(lo), "v"(hi));
  return r;
}

// ---------------- fused cast f32 -> bf16 for all three inputs ----------------
__global__ void cast_all(const float* __restrict__ x, const float* __restrict__ wqkv,
                         const float* __restrict__ wproj, bf16_t* __restrict__ xb,
                         bf16_t* __restrict__ wqkvb, bf16_t* __restrict__ wprojb) {
  int stride = gridDim.x * blockDim.x;
  for (int i = blockIdx.x * blockDim.x + threadIdx.x; i < 3145728; i += stride) {
    const float* src;
    bf16_t* dst;
    int idx;
    if (i < 1048576) { src = x; dst = xb; idx = i; }
    else if (i < 2621440) { src = wqkv; dst = wqkvb; idx = i - 1048576; }
    else { src = wproj; dst = wprojb; idx = i - 2621440; }
    const float* p = src + (size_t)idx * 8;
    f32x4 a = *(const f32x4*)p;
    f32x4 b = *(const f32x4*)(p + 4);
    bf16x8 o;
    o[0] = (bf16_t)a[0]; o[1] = (bf16_t)a[1]; o[2] = (bf16_t)a[2]; o[3] = (bf16_t)a[3];
    o[4] = (bf16_t)b[0]; o[5] = (bf16_t)b[1]; o[6] = (bf16_t)b[2]; o[7] = (bf16_t)b[3];
    *(bf16x8*)(dst + (size_t)idx * 8) = o;
  }
}

// ======== GEMM-QK: 256x256, BK=64, 512thr (8 waves 2Mx4N), 4-phase ========
__global__ __launch_bounds__(512, 2) void gemm_qkv(
    const bf16_t* __restrict__ A, const bf16_t* __restrict__ Bw,
    bf16_t* __restrict__ qo, bf16_t* __restrict__ ko,
    int K) {
  __shared__ __align__(16) char lds[131072];
  int tid = threadIdx.x;
  int w = tid >> 6, lane = tid & 63;
  int wm = w & 1, wn = w >> 1;
  int mr = lane & 15, kg = lane >> 4;

  int orig = blockIdx.x;
  int chunk = orig & 7, i = orig >> 3;
  int by = (chunk & 3) * 4 + (i & 3);
  int bx = (chunk >> 2) * 8 + (i >> 2);
  int row0 = by * 256, col0 = bx * 256;

  int lr = tid >> 3, ch = (tid & 7) ^ (lr & 7);
  size_t aoff[4], boff[4];
#pragma unroll
  for (int g = 0; g < 4; ++g) {
    int gr = g * 32 + (lr & 31) + (lr >> 5) * 128;
    aoff[g] = (size_t)(row0 + gr) * K + ch * 8;
  }
#pragma unroll
  for (int p = 0; p < 4; ++p) {
    int gr = (lr >> 4) * 64 + p * 16 + (lr & 15);
    boff[p] = (size_t)(col0 + gr) * K + ch * 8;
  }

  auto stgA = [&](int q, int g, int kt) {
    async_copy16(A + aoff[g] + kt * 64, lds + q * 65536 + g * 8192 + tid * 16);
  };
  auto stgB = [&](int q, int p, int kt) {
    async_copy16(Bw + boff[p] + kt * 64, lds + q * 65536 + 32768 + p * 8192 + tid * 16);
  };

  f32x4 zero = {0.f, 0.f, 0.f, 0.f};
  f32x4 acc[8][4];
#pragma unroll
  for (int mi = 0; mi < 8; ++mi)
#pragma unroll
    for (int ni = 0; ni < 4; ++ni) acc[mi][ni] = zero;

  int nt = K >> 6;  // 32

  stgB(0, 0, 0); stgB(0, 1, 0); stgB(0, 2, 0); stgB(0, 3, 0);
  stgA(0, 0, 0); stgA(0, 1, 0); stgA(0, 2, 0); stgA(0, 3, 0);
  asm volatile("s_waitcnt vmcnt(0)" ::: "memory");
  __builtin_amdgcn_sched_barrier(0);
  __builtin_amdgcn_s_barrier();
  __builtin_amdgcn_sched_barrier(0);

#pragma unroll 1
  for (int t = 0; t < nt; ++t) {
    int q = t & 1, qn = q ^ 1;
    int kt = (t + 1 < nt) ? (t + 1) : t;
    const char* Ab = lds + q * 65536;
    const char* Bb = Ab + 32768;
    bf16x8 bf[4][2];

#define QKV_PHASE(MI0, STG, DOWAIT)                                             \
    {                                                                           \
      int r0 = ((MI0) >> 1) * 64 + wm * 32 + mr;                                \
      int r1 = r0 + 16;                                                         \
      bf16x8 a00 = *(const bf16x8*)(Ab + r0 * 128 + ((kg * 16) ^ ((r0 & 7) << 4)));      \
      bf16x8 a01 = *(const bf16x8*)(Ab + r0 * 128 + ((64 + kg * 16) ^ ((r0 & 7) << 4))); \
      bf16x8 a10 = *(const bf16x8*)(Ab + r1 * 128 + ((kg * 16) ^ ((r1 & 7) << 4)));      \
      bf16x8 a11 = *(const bf16x8*)(Ab + r1 * 128 + ((64 + kg * 16) ^ ((r1 & 7) << 4))); \
      STG;                                                                      \
      __builtin_amdgcn_sched_barrier(0);                                        \
      if (DOWAIT) { asm volatile("s_waitcnt vmcnt(4)" ::: "memory"); }          \
      __builtin_amdgcn_s_barrier();                                             \
      asm volatile("s_waitcnt lgkmcnt(0)" ::: "memory");                        \
      __builtin_amdgcn_sched_barrier(0);                                        \
      __builtin_amdgcn_s_setprio(1);                                            \
      _Pragma("unroll")                                                         \
      for (int ni = 0; ni < 4; ++ni) {                                          \
        acc[MI0][ni] = MFMA16(a00, bf[ni][0], acc[MI0][ni]);                    \
        acc[MI0][ni] = MFMA16(a01, bf[ni][1], acc[MI0][ni]);                    \
        acc[(MI0) + 1][ni] = MFMA16(a10, bf[ni][0], acc[(MI0) + 1][ni]);        \
        acc[(MI0) + 1][ni] = MFMA16(a11, bf[ni][1], acc[(MI0) + 1][ni]);        \
      }                                                                         \
      __builtin_amdgcn_s_setprio(0);                                            \
      __builtin_amdgcn_sched_barrier(0);                                        \
      __builtin_amdgcn_s_barrier();                                             \
      __builtin_amdgcn_sched_barrier(0);                                        \
    }

#pragma unroll
    for (int ni = 0; ni < 4; ++ni) {
      int rb = ni * 64 + wn * 16 + mr;
      bf[ni][0] = *(const bf16x8*)(Bb + rb * 128 + ((kg * 16) ^ ((rb & 7) << 4)));
      bf[ni][1] = *(const bf16x8*)(Bb + rb * 128 + ((64 + kg * 16) ^ ((rb & 7) << 4)));
    }
    QKV_PHASE(0, (stgA(qn, 0, kt), stgA(qn, 1, kt), stgB(qn, 0, kt), stgB(qn, 1, kt)), 1)
    QKV_PHASE(2, (stgA(qn, 2, kt), stgA(qn, 3, kt), stgB(qn, 2, kt), stgB(qn, 3, kt)), 0)
    QKV_PHASE(4, (void)0, 0)
    QKV_PHASE(6, (void)0, 0)
#undef QKV_PHASE
  }
  asm volatile("s_waitcnt vmcnt(0)" ::: "memory");
  __syncthreads();

  // ---- fused RoPE epilogue (q pre-scaled) ----
  char* tb = &lds[0];
  int s = col0 >> 11;
  int h0 = (col0 >> 7) & 15;
  int b = row0 >> 11, t0 = row0 & 2047;
#pragma unroll
  for (int mi = 0; mi < 8; ++mi)
#pragma unroll
    for (int ni = 0; ni < 4; ++ni)
#pragma unroll
      for (int jj = 0; jj < 4; ++jj) {
        int rl = wm * 128 + mi * 16 + kg * 4 + jj;
        int cb = (wn * 64 + ni * 16 + mr) * 2;
        *(bf16_t*)(tb + rl * 512 + (cb ^ ((rl & 7) << 4))) = (bf16_t)acc[mi][ni][jj];
      }
  __syncthreads();
  int r = tid >> 1, hs = tid & 1;
  const char* rowb = tb + r * 512;
  int sz = (r & 7) << 4;
  int t = t0 + r;
  bf16_t* dst = (s == 0 ? qo : ko) + ((size_t)((b * 16 + h0 + hs) * 2048 + t)) * 128;
  float tf = (float)t;
  const float cinv = -0.20762050593046014f;  // -log2(10000)/64
  float postm = (s == 0) ? 0.12751744f : 1.0f;
  bf16x8 vin[16];
#pragma unroll
  for (int m = 0; m < 16; ++m)
    vin[m] = *(const bf16x8*)(rowb + ((hs * 256 + m * 16) ^ sz));
#pragma unroll
  for (int m = 0; m < 8; ++m) {
    bf16x8 o1, o2;
#pragma unroll
    for (int e = 0; e < 8; ++e) {
      float ang = tf * exp2f((float)(m * 8 + e) * cinv);
      float sv = __sinf(ang), cv = __cosf(ang);
      float x1 = (float)vin[m][e], x2 = (float)vin[m + 8][e];
      o1[e] = (bf16_t)((x1 * cv - x2 * sv) * postm);
      o2[e] = (bf16_t)((x2 * cv + x1 * sv) * postm);
    }
    *(bf16x8*)(dst + m * 8) = o1;
    *(bf16x8*)(dst + 64 + m * 8) = o2;
  }
}

// ------- GEMM 256x128 tile, BK=64, 512 thr, depth-2 (R6 proven body) -------
template <int MODE>
__global__ __launch_bounds__(512, 2) void gemm256(
    const bf16_t* __restrict__ A, const bf16_t* __restrict__ Bw, float* __restrict__ C,
    bf16_t* __restrict__ vto, int M, int N, int K, int nby, int colbase) {
  __shared__ __align__(16) char lds[147456];
  int tid = threadIdx.x;
  int w = tid >> 6, lane = tid & 63;
  int wm = w >> 1, wn = w & 1;
  int mr = lane & 15, kg = lane >> 4;

  int nwg = gridDim.x;
  int orig = blockIdx.x;
  int wgid = (orig & 7) * (nwg >> 3) + (orig >> 3);
  int by = wgid % nby, bx = wgid / nby;
  int row0 = by * 256, col0 = colbase + bx * 128;

  size_t aoff[4], boff[2];
#pragma unroll
  for (int it = 0; it < 4; ++it) {
    int c = tid + it * 512;
    int r = c >> 3;
    int chs = (c & 7) ^ (r & 7);
    aoff[it] = (size_t)(row0 + r) * K + chs * 8;
  }
#pragma unroll
  for (int it = 0; it < 2; ++it) {
    int c = tid + it * 512;
    int r = c >> 3;
    int chs = (c & 7) ^ (r & 7);
    boff[it] = (size_t)(col0 - colbase + r) * K + chs * 8;
  }

  auto stageA = [&](int buf, int kt, int half) {
    char* Ad = &lds[buf * 49152];
#pragma unroll
    for (int it = half * 2; it < half * 2 + 2; ++it)
      async_copy16(A + aoff[it] + kt * 64, Ad + (tid + it * 512) * 16);
  };
  auto stageB = [&](int buf, int kt) {
    char* Bd = &lds[buf * 49152 + 32768];
#pragma unroll
    for (int it = 0; it < 2; ++it)
      async_copy16(Bw + boff[it] + kt * 64, Bd + (tid + it * 512) * 16);
  };

  f32x4 zero = {0.f, 0.f, 0.f, 0.f};
  f32x4 acc[4][4];
#pragma unroll
  for (int mi = 0; mi < 4; ++mi)
#pragma unroll
    for (int ni = 0; ni < 4; ++ni) acc[mi][ni] = zero;

  int nt = K >> 6;
  stageA(0, 0, 0); stageA(0, 0, 1); stageB(0, 0);
  stageA(1, 1, 0); stageA(1, 1, 1); stageB(1, 1);
  asm volatile("s_waitcnt vmcnt(6)" ::: "memory");
  __builtin_amdgcn_sched_barrier(0);
  __builtin_amdgcn_s_barrier();
  __builtin_amdgcn_sched_barrier(0);

#pragma unroll 1
  for (int t = 0; t < nt; ++t) {
    int cur = t % 3;
    int nxt = (t + 2) % 3;
    int kt2 = (t + 2 < nt) ? (t + 2) : t;
    const char* Ab = &lds[cur * 49152];
    const char* Bb = &lds[cur * 49152 + 32768];
    bf16x8 af[4][2], bfr[4][2];
#pragma unroll
    for (int mi = 0; mi < 4; ++mi) {
      int row = wm * 64 + mi * 16 + mr;
      const char* rb = Ab + row * 128;
      int sz = (row & 7) << 4;
      af[mi][0] = *(const bf16x8*)(rb + ((kg * 16) ^ sz));
      af[mi][1] = *(const bf16x8*)(rb + ((64 + kg * 16) ^ sz));
    }
#pragma unroll
    for (int ni = 0; ni < 4; ++ni) {
      int row = wn * 64 + ni * 16 + mr;
      const char* rb = Bb + row * 128;
      int sz = (row & 7) << 4;
      bfr[ni][0] = *(const bf16x8*)(rb + ((kg * 16) ^ sz));
      bfr[ni][1] = *(const bf16x8*)(rb + ((64 + kg * 16) ^ sz));
    }
    stageA(nxt, kt2, 0);
    __builtin_amdgcn_s_setprio(1);
#pragma unroll
    for (int mi = 0; mi < 4; ++mi) {
      acc[mi][0] = MFMA16(af[mi][0], bfr[0][0], acc[mi][0]);
      acc[mi][0] = MFMA16(af[mi][1], bfr[0][1], acc[mi][0]);
    }
    __builtin_amdgcn_s_setprio(0);
    stageA(nxt, kt2, 1);
    __builtin_amdgcn_s_setprio(1);
#pragma unroll
    for (int mi = 0; mi < 4; ++mi) {
      acc[mi][1] = MFMA16(af[mi][0], bfr[1][0], acc[mi][1]);
      acc[mi][1] = MFMA16(af[mi][1], bfr[1][1], acc[mi][1]);
    }
    __builtin_amdgcn_s_setprio(0);
    stageB(nxt, kt2);
    __builtin_amdgcn_s_setprio(1);
#pragma unroll
    for (int mi = 0; mi < 4; ++mi) {
      acc[mi][2] = MFMA16(af[mi][0], bfr[2][0], acc[mi][2]);
      acc[mi][2] = MFMA16(af[mi][1], bfr[2][1], acc[mi][2]);
      acc[mi][3] = MFMA16(af[mi][0], bfr[3][0], acc[mi][3]);
      acc[mi][3] = MFMA16(af[mi][1], bfr[3][1], acc[mi][3]);
    }
    __builtin_amdgcn_s_setprio(0);
    asm volatile("s_waitcnt vmcnt(6)" ::: "memory");
    __builtin_amdgcn_sched_barrier(0);
    __builtin_amdgcn_s_barrier();
    __builtin_amdgcn_sched_barrier(0);
  }
  asm volatile("s_waitcnt vmcnt(0)" ::: "memory");
  __syncthreads();

  if (MODE == 0) {
#pragma unroll
    for (int mi = 0; mi < 4; ++mi)
#pragma unroll
      for (int ni = 0; ni < 4; ++ni)
#pragma unroll
        for (int jj = 0; jj < 4; ++jj) {
          int row = row0 + wm * 64 + mi * 16 + kg * 4 + jj;
          int col = col0 + wn * 64 + ni * 16 + mr;
          C[(size_t)row * N + col] = acc[mi][ni][jj];
        }
  } else {
    char* tb = &lds[0];
    int h = (col0 >> 7) & 15;
    int b = row0 >> 11, t0 = row0 & 2047;
#pragma unroll
    for (int mi = 0; mi < 4; ++mi)
#pragma unroll
      for (int ni = 0; ni < 4; ++ni)
#pragma unroll
        for (int jj = 0; jj < 4; ++jj) {
          int rloc = wm * 64 + mi * 16 + kg * 4 + jj;
          int cloc = wn * 64 + ni * 16 + mr;
          *(bf16_t*)(tb + cloc * 512 + ((rloc * 2) ^ ((cloc & 7) << 4))) =
              (bf16_t)acc[mi][ni][jj];
        }
    __syncthreads();
    int d = tid >> 2, qt = tid & 3;
    const char* rowb = tb + d * 512;
    int sz = (d & 7) << 4;
    bf16_t* dst = vto + ((size_t)((b * 16 + h) * 128 + d)) * 2048 + t0 + qt * 64;
#pragma unroll
    for (int m2 = 0; m2 < 8; ++m2)
      *(bf16x8*)(dst + m2 * 8) = *(const bf16x8*)(rowb + ((qt * 128 + m2 * 16) ^ sz));
  }
}

// ---------------- causal flash attention (v10: T15 pipelined) ----------------
// v8 math with software pipeline: iter j computes QK(j+1) (MFMA) interleaved
// with softmax(j) (VALU) in one straight-line block (activity guard removed —
// causal mask makes inactive tiles exact zeros). K 3-deep, V 2-deep buffers
// (80KB = 2 blocks/CU). Steady-state vmcnt(8) confirms {K[j+1],V[j]}, both
// staged 2 iterations earlier; tail drains.
__global__ __launch_bounds__(256, 2) void attn_kernel(
    const bf16_t* __restrict__ qg, const bf16_t* __restrict__ kgl,
    const bf16_t* __restrict__ vtg, bf16_t* __restrict__ og) {
  __shared__ __align__(16) bf16_t Ks[3][64 * 128];
  __shared__ __align__(16) bf16_t Vs[2][128 * 64];
  const int T = 2048;
  int tid = threadIdx.x;
  int w = tid >> 6, lane = tid & 63;
  int l31 = lane & 31, hi = lane >> 5;

  int L = blockIdx.x;
  int halfg = L >> 8;
  int Lr = L & 255;
  int role = (Lr & 7) * 32 + (Lr >> 3);
  int bx = role & 7, bh = role >> 3;
  int qb = halfg ? bx : (15 - bx);

  const bf16_t* Q = qg + (size_t)bh * T * 128;
  const bf16_t* K = kgl + (size_t)bh * T * 128;
  const bf16_t* Vt = vtg + (size_t)bh * 128 * T;

  int sb = tid * 16;
  int krl = sb >> 8;
  int kc = (sb & 255) ^ (krl << 4);
  size_t ksrc = (size_t)krl * 128 + (kc >> 1);
  int vdl = sb >> 7;
  int vc = (sb & 127) ^ ((vdl & 7) << 4);
  size_t vsrc = (size_t)vdl * 2048 + (vc >> 1);

  auto stageK = [&](int buf, int kb) {
#pragma unroll
    for (int it = 0; it < 4; ++it)
      async_copy16(K + (size_t)(kb + it * 16) * 128 + ksrc, &Ks[buf][it * 2048 + tid * 8]);
  };
  auto stageV = [&](int buf, int kb) {
#pragma unroll
    for (int it = 0; it < 4; ++it)
      async_copy16(Vt + (size_t)it * 65536 + kb + vsrc, &Vs[buf][it * 2048 + tid * 8]);
  };

  int b = bh >> 4, h = bh & 15;
  f32x16 zero16 = {0.f};
  int swzK = (l31 & 15) << 4;
  int swzV = (l31 & 7) << 4;

  int qw0 = qb * 128 + w * 32;
  int tq = qw0 + l31;
  const bf16_t* qrow = Q + (size_t)tq * 128 + hi * 8;
  bf16x8 qf[8];
#pragma unroll
  for (int dc = 0; dc < 8; ++dc) qf[dc] = *(const bf16x8*)(qrow + dc * 16);

  f32x16 acc[4];
#pragma unroll
  for (int dt = 0; dt < 4; ++dt) acc[dt] = zero16;
  float mrun = -1e30f, lpart = 0.f;

#define QK_TILE(BUF, S0, S1)                                                   \
  { const char* KsB_ = (const char*)&Ks[BUF][0];                               \
    _Pragma("unroll")                                                          \
    for (int dc = 0; dc < 8; ++dc) {                                           \
      int cb = dc * 32 + hi * 16;                                              \
      bf16x8 k0_ = *(const bf16x8*)(KsB_ + l31 * 256 + (cb ^ swzK));           \
      bf16x8 k1_ = *(const bf16x8*)(KsB_ + (32 + l31) * 256 + (cb ^ swzK));    \
      S0 = MFMA32(k0_, qf[dc], S0);                                            \
      S1 = MFMA32(k1_, qf[dc], S1);                                            \
    } }

  int nj = 2 * qb + 2;
  // prologue: K0, V0, K1, V1 [, K2]; wait leaves younger loads in flight
  stageK(0, 0);
  stageV(0, 0);
  stageK(1, 64);
  stageV(1, 64);
  if (nj > 2) {
    stageK(2, 128);
    asm volatile("s_waitcnt vmcnt(16)" ::: "memory");  // K0 landed
  } else {
    asm volatile("s_waitcnt vmcnt(12)" ::: "memory");  // K0 landed
  }
  __builtin_amdgcn_sched_barrier(0);
  __syncthreads();
  f32x16 sc0 = zero16, sc1 = zero16;  // S(0)
  QK_TILE(0, sc0, sc1)

#pragma unroll 1
  for (int j = 0; j < nj; ++j) {
    int kb = j * 64;
    // wait: steady-state outstanding = V[j+1](4) + K[j+2](4); tail drains
    if (j + 2 < nj) {
      asm volatile("s_waitcnt vmcnt(8)" ::: "memory");
    } else {
      asm volatile("s_waitcnt vmcnt(0)" ::: "memory");
    }
    __builtin_amdgcn_sched_barrier(0);
    __syncthreads();
    // ---- QK(j+1) MFMA (independent) + softmax(j) VALU: one block ----
    f32x16 sn0 = zero16, sn1 = zero16;
    if (j + 1 < nj) {
      QK_TILE((j + 1) % 3, sn0, sn1)
    }
    // softmax on sc (tile j); causal mask also zeroes fully-inactive waves
    float p0[16], p1[16];
    float lmax = -3e38f;
    bool diag = (kb + 63 > qw0);
#pragma unroll
    for (int r = 0; r < 16; ++r) {
      int kk = (r & 3) + 8 * (r >> 2) + 4 * hi;
      float v0 = sc0[r], v1 = sc1[r];
      if (diag) {
        if (kb + kk > tq) v0 = -1e30f;
        if (kb + 32 + kk > tq) v1 = -1e30f;
      }
      p0[r] = v0; p1[r] = v1;
      lmax = fmaxf(lmax, fmaxf(v0, v1));
    }
    bool ok = (lmax <= mrun + 8.0f);
    if (!__all(ok)) {
      float tmax = fmaxf(lmax, __shfl_xor(lmax, 32, 64));
      float mn = fmaxf(mrun, tmax);
      float corr = __builtin_amdgcn_exp2f(mrun - mn);
      mrun = mn;
      lpart *= corr;
#pragma unroll
      for (int dt = 0; dt < 4; ++dt)
#pragma unroll
        for (int r = 0; r < 16; ++r) acc[dt][r] *= corr;
    }
#pragma unroll
    for (int r = 0; r < 16; ++r) {
      float e0 = __builtin_amdgcn_exp2f(p0[r] - mrun);
      float e1 = __builtin_amdgcn_exp2f(p1[r] - mrun);
      p0[r] = e0; p1[r] = e1;
      lpart += e0 + e1;
    }
    bf16x8 pa0, pa1, pa2, pa3;
#define BUILD_PA(dst, P, B0)                                         \
    { unsigned a0 = cvtpk(P[(B0) + 0], P[(B0) + 1]);                 \
      unsigned a1 = cvtpk(P[(B0) + 2], P[(B0) + 3]);                 \
      unsigned b0 = cvtpk(P[(B0) + 4], P[(B0) + 5]);                 \
      unsigned b1 = cvtpk(P[(B0) + 6], P[(B0) + 7]);                 \
      unsigned xa0 = __shfl_xor(a0, 32, 64);                         \
      unsigned xa1 = __shfl_xor(a1, 32, 64);                         \
      unsigned xb0 = __shfl_xor(b0, 32, 64);                         \
      unsigned xb1 = __shfl_xor(b1, 32, 64);                         \
      u32x4v fw;                                                     \
      fw[0] = hi ? xb0 : a0; fw[1] = hi ? xb1 : a1;                  \
      fw[2] = hi ? b0 : xa0; fw[3] = hi ? b1 : xa1;                  \
      dst = __builtin_bit_cast(bf16x8, fw); }
    BUILD_PA(pa0, p0, 0)
    BUILD_PA(pa1, p0, 8)
    BUILD_PA(pa2, p1, 0)
    BUILD_PA(pa3, p1, 8)
#undef BUILD_PA
    {
      const char* VsB = (const char*)&Vs[j & 1][0];
      __builtin_amdgcn_s_setprio(1);
#pragma unroll
      for (int dt = 0; dt < 4; ++dt) {
        const char* vrow = VsB + (dt * 32 + l31) * 128;
        bf16x8 v0 = *(const bf16x8*)(vrow + ((hi * 16) ^ swzV));
        bf16x8 v1 = *(const bf16x8*)(vrow + ((32 + hi * 16) ^ swzV));
        bf16x8 v2 = *(const bf16x8*)(vrow + ((64 + hi * 16) ^ swzV));
        bf16x8 v3 = *(const bf16x8*)(vrow + ((96 + hi * 16) ^ swzV));
        acc[dt] = MFMA32(v0, pa0, acc[dt]);
        acc[dt] = MFMA32(v1, pa1, acc[dt]);
        acc[dt] = MFMA32(v2, pa2, acc[dt]);
        acc[dt] = MFMA32(v3, pa3, acc[dt]);
      }
      __builtin_amdgcn_s_setprio(0);
    }
    __syncthreads();
    if (j + 2 < nj) stageV(j & 1, (j + 2) * 64);
    if (j + 3 < nj) stageK((j + 3) % 3, (j + 3) * 64);
    sc0 = sn0;
    sc1 = sn1;
  }
#undef QK_TILE
  // ---- epilogue: l = own + partner; store O[q][d] scrambled ----
  float l = lpart + __shfl_xor(lpart, 32, 64);
  float invl = 1.0f / l;
  size_t orow_idx = (size_t)b * 2048 + h * 128 + (tq >> 4);
  bf16_t* orow = og + orow_idx * 2048 + (tq & 15) * 128;
#pragma unroll
  for (int dt = 0; dt < 4; ++dt)
#pragma unroll
    for (int g = 0; g < 4; ++g) {
      bf16x4 v4;
#pragma unroll
      for (int e = 0; e < 4; ++e) v4[e] = (bf16_t)(acc[dt][4 * g + e] * invl);
      *(bf16x4*)(orow + dt * 32 + 8 * g + 4 * hi) = v4;
    }
}

extern "C" void kernel_launch(void* const* d_in, const int* in_sizes, int n_in,
                              void* d_out, int out_size, void* d_ws, size_t ws_size,
                              hipStream_t stream) {
  const float* x = (const float*)d_in[0];      // [2,2048,2048]
  const float* wqkv = (const float*)d_in[1];   // [6144,2048]
  const float* wproj = (const float*)d_in[2];  // [2048,2048]
  float* out = (float*)d_out;                  // [2,2048,2048]
  char* ws = (char*)d_ws;

  const size_t OFF_WQKV = 16777216;
  const size_t OFF_WPROJ = 41943040;
  const size_t OFF_Q = 50331648;
  const size_t OFF_K = 67108864;
  const size_t OFF_VT = 83886080;

  bf16_t* xb = (bf16_t*)(ws);
  bf16_t* wqkvb = (bf16_t*)(ws + OFF_WQKV);
  bf16_t* wprojb = (bf16_t*)(ws + OFF_WPROJ);
  bf16_t* g_q = (bf16_t*)(ws + OFF_Q);
  bf16_t* g_k = (bf16_t*)(ws + OFF_K);
  bf16_t* g_vt = (bf16_t*)(ws + OFF_VT);
  bf16_t* g_att = (bf16_t*)(ws);               // alias xb (dead after gemms)

  cast_all<<<4096, 256, 0, stream>>>(x, wqkv, wproj, xb, wqkvb, wprojb);
  gemm_qkv<<<256, 512, 0, stream>>>(xb, wqkvb, g_q, g_k, 2048);
  gemm256<1><<<256, 512, 0, stream>>>(xb, wqkvb + (size_t)4096 * 2048, nullptr, g_vt,
                                      4096, 2048, 2048, 16, 4096);
  // attn v10: T15-pipelined (QK(j+1) overlaps softmax(j)), 512 blocks
  attn_kernel<<<512, 256, 0, stream>>>(g_q, g_k, g_vt, g_att);
  gemm256<0><<<256, 512, 0, stream>>>(g_att, wprojb, out, nullptr, 4096, 2048, 2048, 16, 0);
}

// Round 22
// 241.606 us; speedup vs baseline: 1.0202x; 1.0034x over previous
//
#include <hip/hip_runtime.h>
#include <hip/hip_bf16.h>

typedef __bf16 bf16_t;
typedef __bf16 bf16x8 __attribute__((ext_vector_type(8)));
typedef __bf16 bf16x4 __attribute__((ext_vector_type(4)));
typedef float f32x4 __attribute__((ext_vector_type(4)));
typedef float f32x16 __attribute__((ext_vector_type(16)));
typedef unsigned u32x4v __attribute__((ext_vector_type(4)));

#define MFMA16(a, b, c) __builtin_amdgcn_mfma_f32_16x16x32_bf16(a, b, c, 0, 0, 0)
#define MFMA32(a, b, c) __builtin_amdgcn_mfma_f32_32x32x16_bf16(a, b, c, 0, 0, 0)

__device__ __forceinline__ void async_copy16(const void* g, void* l) {
  __builtin_amdgcn_global_load_lds(
      (const __attribute__((address_space(1))) void*)g,
      (__attribute__((address_space(3))) void*)l, 16, 0, 0);
}

__device__ __forceinline__ unsigned cvtpk(float lo, float hi) {
  unsigned r;
  asm("v_cvt_pk_bf16_f32 %0, %1, %2" : "=v"(r) : "v"(lo), "v"(hi));
  return r;
}

// ---------------- fused cast f32 -> bf16 for all three inputs ----------------
__global__ void cast_all(const float* __restrict__ x, const float* __restrict__ wqkv,
                         const float* __restrict__ wproj, bf16_t* __restrict__ xb,
                         bf16_t* __restrict__ wqkvb, bf16_t* __restrict__ wprojb) {
  int stride = gridDim.x * blockDim.x;
  for (int i = blockIdx.x * blockDim.x + threadIdx.x; i < 3145728; i += stride) {
    const float* src;
    bf16_t* dst;
    int idx;
    if (i < 1048576) { src = x; dst = xb; idx = i; }
    else if (i < 2621440) { src = wqkv; dst = wqkvb; idx = i - 1048576; }
    else { src = wproj; dst = wprojb; idx = i - 2621440; }
    const float* p = src + (size_t)idx * 8;
    f32x4 a = *(const f32x4*)p;
    f32x4 b = *(const f32x4*)(p + 4);
    bf16x8 o;
    o[0] = (bf16_t)a[0]; o[1] = (bf16_t)a[1]; o[2] = (bf16_t)a[2]; o[3] = (bf16_t)a[3];
    o[4] = (bf16_t)b[0]; o[5] = (bf16_t)b[1]; o[6] = (bf16_t)b[2]; o[7] = (bf16_t)b[3];
    *(bf16x8*)(dst + (size_t)idx * 8) = o;
  }
}

// ======== GEMM-QK: 256x256, BK=64, 512thr (8 waves 2Mx4N), 4-phase ========
__global__ __launch_bounds__(512, 2) void gemm_qkv(
    const bf16_t* __restrict__ A, const bf16_t* __restrict__ Bw,
    bf16_t* __restrict__ qo, bf16_t* __restrict__ ko,
    int K) {
  __shared__ __align__(16) char lds[131072];
  int tid = threadIdx.x;
  int w = tid >> 6, lane = tid & 63;
  int wm = w & 1, wn = w >> 1;
  int mr = lane & 15, kg = lane >> 4;

  int orig = blockIdx.x;
  int chunk = orig & 7, i = orig >> 3;
  int by = (chunk & 3) * 4 + (i & 3);
  int bx = (chunk >> 2) * 8 + (i >> 2);
  int row0 = by * 256, col0 = bx * 256;

  int lr = tid >> 3, ch = (tid & 7) ^ (lr & 7);
  size_t aoff[4], boff[4];
#pragma unroll
  for (int g = 0; g < 4; ++g) {
    int gr = g * 32 + (lr & 31) + (lr >> 5) * 128;
    aoff[g] = (size_t)(row0 + gr) * K + ch * 8;
  }
#pragma unroll
  for (int p = 0; p < 4; ++p) {
    int gr = (lr >> 4) * 64 + p * 16 + (lr & 15);
    boff[p] = (size_t)(col0 + gr) * K + ch * 8;
  }

  auto stgA = [&](int q, int g, int kt) {
    async_copy16(A + aoff[g] + kt * 64, lds + q * 65536 + g * 8192 + tid * 16);
  };
  auto stgB = [&](int q, int p, int kt) {
    async_copy16(Bw + boff[p] + kt * 64, lds + q * 65536 + 32768 + p * 8192 + tid * 16);
  };

  f32x4 zero = {0.f, 0.f, 0.f, 0.f};
  f32x4 acc[8][4];
#pragma unroll
  for (int mi = 0; mi < 8; ++mi)
#pragma unroll
    for (int ni = 0; ni < 4; ++ni) acc[mi][ni] = zero;

  int nt = K >> 6;  // 32

  stgB(0, 0, 0); stgB(0, 1, 0); stgB(0, 2, 0); stgB(0, 3, 0);
  stgA(0, 0, 0); stgA(0, 1, 0); stgA(0, 2, 0); stgA(0, 3, 0);
  asm volatile("s_waitcnt vmcnt(0)" ::: "memory");
  __builtin_amdgcn_sched_barrier(0);
  __builtin_amdgcn_s_barrier();
  __builtin_amdgcn_sched_barrier(0);

#pragma unroll 1
  for (int t = 0; t < nt; ++t) {
    int q = t & 1, qn = q ^ 1;
    int kt = (t + 1 < nt) ? (t + 1) : t;
    const char* Ab = lds + q * 65536;
    const char* Bb = Ab + 32768;
    bf16x8 bf[4][2];

#define QKV_PHASE(MI0, STG, DOWAIT)                                             \
    {                                                                           \
      int r0 = ((MI0) >> 1) * 64 + wm * 32 + mr;                                \
      int r1 = r0 + 16;                                                         \
      bf16x8 a00 = *(const bf16x8*)(Ab + r0 * 128 + ((kg * 16) ^ ((r0 & 7) << 4)));      \
      bf16x8 a01 = *(const bf16x8*)(Ab + r0 * 128 + ((64 + kg * 16) ^ ((r0 & 7) << 4))); \
      bf16x8 a10 = *(const bf16x8*)(Ab + r1 * 128 + ((kg * 16) ^ ((r1 & 7) << 4)));      \
      bf16x8 a11 = *(const bf16x8*)(Ab + r1 * 128 + ((64 + kg * 16) ^ ((r1 & 7) << 4))); \
      STG;                                                                      \
      __builtin_amdgcn_sched_barrier(0);                                        \
      if (DOWAIT) { asm volatile("s_waitcnt vmcnt(4)" ::: "memory"); }          \
      __builtin_amdgcn_s_barrier();                                             \
      asm volatile("s_waitcnt lgkmcnt(0)" ::: "memory");                        \
      __builtin_amdgcn_sched_barrier(0);                                        \
      __builtin_amdgcn_s_setprio(1);                                            \
      _Pragma("unroll")                                                         \
      for (int ni = 0; ni < 4; ++ni) {                                          \
        acc[MI0][ni] = MFMA16(a00, bf[ni][0], acc[MI0][ni]);                    \
        acc[MI0][ni] = MFMA16(a01, bf[ni][1], acc[MI0][ni]);                    \
        acc[(MI0) + 1][ni] = MFMA16(a10, bf[ni][0], acc[(MI0) + 1][ni]);        \
        acc[(MI0) + 1][ni] = MFMA16(a11, bf[ni][1], acc[(MI0) + 1][ni]);        \
      }                                                                         \
      __builtin_amdgcn_s_setprio(0);                                            \
      __builtin_amdgcn_sched_barrier(0);                                        \
      __builtin_amdgcn_s_barrier();                                             \
      __builtin_amdgcn_sched_barrier(0);                                        \
    }

#pragma unroll
    for (int ni = 0; ni < 4; ++ni) {
      int rb = ni * 64 + wn * 16 + mr;
      bf[ni][0] = *(const bf16x8*)(Bb + rb * 128 + ((kg * 16) ^ ((rb & 7) << 4)));
      bf[ni][1] = *(const bf16x8*)(Bb + rb * 128 + ((64 + kg * 16) ^ ((rb & 7) << 4)));
    }
    QKV_PHASE(0, (stgA(qn, 0, kt), stgA(qn, 1, kt), stgB(qn, 0, kt), stgB(qn, 1, kt)), 1)
    QKV_PHASE(2, (stgA(qn, 2, kt), stgA(qn, 3, kt), stgB(qn, 2, kt), stgB(qn, 3, kt)), 0)
    QKV_PHASE(4, (void)0, 0)
    QKV_PHASE(6, (void)0, 0)
#undef QKV_PHASE
  }
  asm volatile("s_waitcnt vmcnt(0)" ::: "memory");
  __syncthreads();

  // ---- fused RoPE epilogue (q pre-scaled) ----
  char* tb = &lds[0];
  int s = col0 >> 11;
  int h0 = (col0 >> 7) & 15;
  int b = row0 >> 11, t0 = row0 & 2047;
#pragma unroll
  for (int mi = 0; mi < 8; ++mi)
#pragma unroll
    for (int ni = 0; ni < 4; ++ni)
#pragma unroll
      for (int jj = 0; jj < 4; ++jj) {
        int rl = wm * 128 + mi * 16 + kg * 4 + jj;
        int cb = (wn * 64 + ni * 16 + mr) * 2;
        *(bf16_t*)(tb + rl * 512 + (cb ^ ((rl & 7) << 4))) = (bf16_t)acc[mi][ni][jj];
      }
  __syncthreads();
  int r = tid >> 1, hs = tid & 1;
  const char* rowb = tb + r * 512;
  int sz = (r & 7) << 4;
  int t = t0 + r;
  bf16_t* dst = (s == 0 ? qo : ko) + ((size_t)((b * 16 + h0 + hs) * 2048 + t)) * 128;
  float tf = (float)t;
  const float cinv = -0.20762050593046014f;  // -log2(10000)/64
  float postm = (s == 0) ? 0.12751744f : 1.0f;
  bf16x8 vin[16];
#pragma unroll
  for (int m = 0; m < 16; ++m)
    vin[m] = *(const bf16x8*)(rowb + ((hs * 256 + m * 16) ^ sz));
#pragma unroll
  for (int m = 0; m < 8; ++m) {
    bf16x8 o1, o2;
#pragma unroll
    for (int e = 0; e < 8; ++e) {
      float ang = tf * exp2f((float)(m * 8 + e) * cinv);
      float sv = __sinf(ang), cv = __cosf(ang);
      float x1 = (float)vin[m][e], x2 = (float)vin[m + 8][e];
      o1[e] = (bf16_t)((x1 * cv - x2 * sv) * postm);
      o2[e] = (bf16_t)((x2 * cv + x1 * sv) * postm);
    }
    *(bf16x8*)(dst + m * 8) = o1;
    *(bf16x8*)(dst + 64 + m * 8) = o2;
  }
}

// ------- GEMM 256x128 tile, BK=64, 512 thr, depth-2 (R6 proven body) -------
template <int MODE>
__global__ __launch_bounds__(512, 2) void gemm256(
    const bf16_t* __restrict__ A, const bf16_t* __restrict__ Bw, float* __restrict__ C,
    bf16_t* __restrict__ vto, int M, int N, int K, int nby, int colbase) {
  __shared__ __align__(16) char lds[147456];
  int tid = threadIdx.x;
  int w = tid >> 6, lane = tid & 63;
  int wm = w >> 1, wn = w & 1;
  int mr = lane & 15, kg = lane >> 4;

  int nwg = gridDim.x;
  int orig = blockIdx.x;
  int wgid = (orig & 7) * (nwg >> 3) + (orig >> 3);
  int by = wgid % nby, bx = wgid / nby;
  int row0 = by * 256, col0 = colbase + bx * 128;

  size_t aoff[4], boff[2];
#pragma unroll
  for (int it = 0; it < 4; ++it) {
    int c = tid + it * 512;
    int r = c >> 3;
    int chs = (c & 7) ^ (r & 7);
    aoff[it] = (size_t)(row0 + r) * K + chs * 8;
  }
#pragma unroll
  for (int it = 0; it < 2; ++it) {
    int c = tid + it * 512;
    int r = c >> 3;
    int chs = (c & 7) ^ (r & 7);
    boff[it] = (size_t)(col0 - colbase + r) * K + chs * 8;
  }

  auto stageA = [&](int buf, int kt, int half) {
    char* Ad = &lds[buf * 49152];
#pragma unroll
    for (int it = half * 2; it < half * 2 + 2; ++it)
      async_copy16(A + aoff[it] + kt * 64, Ad + (tid + it * 512) * 16);
  };
  auto stageB = [&](int buf, int kt) {
    char* Bd = &lds[buf * 49152 + 32768];
#pragma unroll
    for (int it = 0; it < 2; ++it)
      async_copy16(Bw + boff[it] + kt * 64, Bd + (tid + it * 512) * 16);
  };

  f32x4 zero = {0.f, 0.f, 0.f, 0.f};
  f32x4 acc[4][4];
#pragma unroll
  for (int mi = 0; mi < 4; ++mi)
#pragma unroll
    for (int ni = 0; ni < 4; ++ni) acc[mi][ni] = zero;

  int nt = K >> 6;
  stageA(0, 0, 0); stageA(0, 0, 1); stageB(0, 0);
  stageA(1, 1, 0); stageA(1, 1, 1); stageB(1, 1);
  asm volatile("s_waitcnt vmcnt(6)" ::: "memory");
  __builtin_amdgcn_sched_barrier(0);
  __builtin_amdgcn_s_barrier();
  __builtin_amdgcn_sched_barrier(0);

#pragma unroll 1
  for (int t = 0; t < nt; ++t) {
    int cur = t % 3;
    int nxt = (t + 2) % 3;
    int kt2 = (t + 2 < nt) ? (t + 2) : t;
    const char* Ab = &lds[cur * 49152];
    const char* Bb = &lds[cur * 49152 + 32768];
    bf16x8 af[4][2], bfr[4][2];
#pragma unroll
    for (int mi = 0; mi < 4; ++mi) {
      int row = wm * 64 + mi * 16 + mr;
      const char* rb = Ab + row * 128;
      int sz = (row & 7) << 4;
      af[mi][0] = *(const bf16x8*)(rb + ((kg * 16) ^ sz));
      af[mi][1] = *(const bf16x8*)(rb + ((64 + kg * 16) ^ sz));
    }
#pragma unroll
    for (int ni = 0; ni < 4; ++ni) {
      int row = wn * 64 + ni * 16 + mr;
      const char* rb = Bb + row * 128;
      int sz = (row & 7) << 4;
      bfr[ni][0] = *(const bf16x8*)(rb + ((kg * 16) ^ sz));
      bfr[ni][1] = *(const bf16x8*)(rb + ((64 + kg * 16) ^ sz));
    }
    stageA(nxt, kt2, 0);
    __builtin_amdgcn_s_setprio(1);
#pragma unroll
    for (int mi = 0; mi < 4; ++mi) {
      acc[mi][0] = MFMA16(af[mi][0], bfr[0][0], acc[mi][0]);
      acc[mi][0] = MFMA16(af[mi][1], bfr[0][1], acc[mi][0]);
    }
    __builtin_amdgcn_s_setprio(0);
    stageA(nxt, kt2, 1);
    __builtin_amdgcn_s_setprio(1);
#pragma unroll
    for (int mi = 0; mi < 4; ++mi) {
      acc[mi][1] = MFMA16(af[mi][0], bfr[1][0], acc[mi][1]);
      acc[mi][1] = MFMA16(af[mi][1], bfr[1][1], acc[mi][1]);
    }
    __builtin_amdgcn_s_setprio(0);
    stageB(nxt, kt2);
    __builtin_amdgcn_s_setprio(1);
#pragma unroll
    for (int mi = 0; mi < 4; ++mi) {
      acc[mi][2] = MFMA16(af[mi][0], bfr[2][0], acc[mi][2]);
      acc[mi][2] = MFMA16(af[mi][1], bfr[2][1], acc[mi][2]);
      acc[mi][3] = MFMA16(af[mi][0], bfr[3][0], acc[mi][3]);
      acc[mi][3] = MFMA16(af[mi][1], bfr[3][1], acc[mi][3]);
    }
    __builtin_amdgcn_s_setprio(0);
    asm volatile("s_waitcnt vmcnt(6)" ::: "memory");
    __builtin_amdgcn_sched_barrier(0);
    __builtin_amdgcn_s_barrier();
    __builtin_amdgcn_sched_barrier(0);
  }
  asm volatile("s_waitcnt vmcnt(0)" ::: "memory");
  __syncthreads();

  if (MODE == 0) {
#pragma unroll
    for (int mi = 0; mi < 4; ++mi)
#pragma unroll
      for (int ni = 0; ni < 4; ++ni)
#pragma unroll
        for (int jj = 0; jj < 4; ++jj) {
          int row = row0 + wm * 64 + mi * 16 + kg * 4 + jj;
          int col = col0 + wn * 64 + ni * 16 + mr;
          C[(size_t)row * N + col] = acc[mi][ni][jj];
        }
  } else {
    char* tb = &lds[0];
    int h = (col0 >> 7) & 15;
    int b = row0 >> 11, t0 = row0 & 2047;
#pragma unroll
    for (int mi = 0; mi < 4; ++mi)
#pragma unroll
      for (int ni = 0; ni < 4; ++ni)
#pragma unroll
        for (int jj = 0; jj < 4; ++jj) {
          int rloc = wm * 64 + mi * 16 + kg * 4 + jj;
          int cloc = wn * 64 + ni * 16 + mr;
          *(bf16_t*)(tb + cloc * 512 + ((rloc * 2) ^ ((cloc & 7) << 4))) =
              (bf16_t)acc[mi][ni][jj];
        }
    __syncthreads();
    int d = tid >> 2, qt = tid & 3;
    const char* rowb = tb + d * 512;
    int sz = (d & 7) << 4;
    bf16_t* dst = vto + ((size_t)((b * 16 + h) * 128 + d)) * 2048 + t0 + qt * 64;
#pragma unroll
    for (int m2 = 0; m2 < 8; ++m2)
      *(bf16x8*)(dst + m2 * 8) = *(const bf16x8*)(rowb + ((qt * 128 + m2 * 16) ^ sz));
  }
}

// ---------------- causal flash attention (v10: T15 pipelined, final) ----------------
__global__ __launch_bounds__(256, 2) void attn_kernel(
    const bf16_t* __restrict__ qg, const bf16_t* __restrict__ kgl,
    const bf16_t* __restrict__ vtg, bf16_t* __restrict__ og) {
  __shared__ __align__(16) bf16_t Ks[3][64 * 128];
  __shared__ __align__(16) bf16_t Vs[2][128 * 64];
  const int T = 2048;
  int tid = threadIdx.x;
  int w = tid >> 6, lane = tid & 63;
  int l31 = lane & 31, hi = lane >> 5;

  int L = blockIdx.x;
  int halfg = L >> 8;
  int Lr = L & 255;
  int role = (Lr & 7) * 32 + (Lr >> 3);
  int bx = role & 7, bh = role >> 3;
  int qb = halfg ? bx : (15 - bx);

  const bf16_t* Q = qg + (size_t)bh * T * 128;
  const bf16_t* K = kgl + (size_t)bh * T * 128;
  const bf16_t* Vt = vtg + (size_t)bh * 128 * T;

  int sb = tid * 16;
  int krl = sb >> 8;
  int kc = (sb & 255) ^ (krl << 4);
  size_t ksrc = (size_t)krl * 128 + (kc >> 1);
  int vdl = sb >> 7;
  int vc = (sb & 127) ^ ((vdl & 7) << 4);
  size_t vsrc = (size_t)vdl * 2048 + (vc >> 1);

  auto stageK = [&](int buf, int kb) {
#pragma unroll
    for (int it = 0; it < 4; ++it)
      async_copy16(K + (size_t)(kb + it * 16) * 128 + ksrc, &Ks[buf][it * 2048 + tid * 8]);
  };
  auto stageV = [&](int buf, int kb) {
#pragma unroll
    for (int it = 0; it < 4; ++it)
      async_copy16(Vt + (size_t)it * 65536 + kb + vsrc, &Vs[buf][it * 2048 + tid * 8]);
  };

  int b = bh >> 4, h = bh & 15;
  f32x16 zero16 = {0.f};
  int swzK = (l31 & 15) << 4;
  int swzV = (l31 & 7) << 4;

  int qw0 = qb * 128 + w * 32;
  int tq = qw0 + l31;
  const bf16_t* qrow = Q + (size_t)tq * 128 + hi * 8;
  bf16x8 qf[8];
#pragma unroll
  for (int dc = 0; dc < 8; ++dc) qf[dc] = *(const bf16x8*)(qrow + dc * 16);

  f32x16 acc[4];
#pragma unroll
  for (int dt = 0; dt < 4; ++dt) acc[dt] = zero16;
  float mrun = -1e30f, lpart = 0.f;

#define QK_TILE(BUF, S0, S1)                                                   \
  { const char* KsB_ = (const char*)&Ks[BUF][0];                               \
    _Pragma("unroll")                                                          \
    for (int dc = 0; dc < 8; ++dc) {                                           \
      int cb = dc * 32 + hi * 16;                                              \
      bf16x8 k0_ = *(const bf16x8*)(KsB_ + l31 * 256 + (cb ^ swzK));           \
      bf16x8 k1_ = *(const bf16x8*)(KsB_ + (32 + l31) * 256 + (cb ^ swzK));    \
      S0 = MFMA32(k0_, qf[dc], S0);                                            \
      S1 = MFMA32(k1_, qf[dc], S1);                                            \
    } }

  int nj = 2 * qb + 2;
  stageK(0, 0);
  stageV(0, 0);
  stageK(1, 64);
  stageV(1, 64);
  if (nj > 2) {
    stageK(2, 128);
    asm volatile("s_waitcnt vmcnt(16)" ::: "memory");  // K0 landed
  } else {
    asm volatile("s_waitcnt vmcnt(12)" ::: "memory");  // K0 landed
  }
  __builtin_amdgcn_sched_barrier(0);
  __syncthreads();
  f32x16 sc0 = zero16, sc1 = zero16;  // S(0)
  QK_TILE(0, sc0, sc1)

#pragma unroll 1
  for (int j = 0; j < nj; ++j) {
    int kb = j * 64;
    if (j + 2 < nj) {
      asm volatile("s_waitcnt vmcnt(8)" ::: "memory");
    } else {
      asm volatile("s_waitcnt vmcnt(0)" ::: "memory");
    }
    __builtin_amdgcn_sched_barrier(0);
    __syncthreads();
    // ---- QK(j+1) MFMA (independent) + softmax(j) VALU: one block ----
    f32x16 sn0 = zero16, sn1 = zero16;
    if (j + 1 < nj) {
      QK_TILE((j + 1) % 3, sn0, sn1)
    }
    float p0[16], p1[16];
    float lmax = -3e38f;
    bool diag = (kb + 63 > qw0);
#pragma unroll
    for (int r = 0; r < 16; ++r) {
      int kk = (r & 3) + 8 * (r >> 2) + 4 * hi;
      float v0 = sc0[r], v1 = sc1[r];
      if (diag) {
        if (kb + kk > tq) v0 = -1e30f;
        if (kb + 32 + kk > tq) v1 = -1e30f;
      }
      p0[r] = v0; p1[r] = v1;
      lmax = fmaxf(lmax, fmaxf(v0, v1));
    }
    bool ok = (lmax <= mrun + 8.0f);
    if (!__all(ok)) {
      float tmax = fmaxf(lmax, __shfl_xor(lmax, 32, 64));
      float mn = fmaxf(mrun, tmax);
      float corr = __builtin_amdgcn_exp2f(mrun - mn);
      mrun = mn;
      lpart *= corr;
#pragma unroll
      for (int dt = 0; dt < 4; ++dt)
#pragma unroll
        for (int r = 0; r < 16; ++r) acc[dt][r] *= corr;
    }
#pragma unroll
    for (int r = 0; r < 16; ++r) {
      float e0 = __builtin_amdgcn_exp2f(p0[r] - mrun);
      float e1 = __builtin_amdgcn_exp2f(p1[r] - mrun);
      p0[r] = e0; p1[r] = e1;
      lpart += e0 + e1;
    }
    bf16x8 pa0, pa1, pa2, pa3;
#define BUILD_PA(dst, P, B0)                                         \
    { unsigned a0 = cvtpk(P[(B0) + 0], P[(B0) + 1]);                 \
      unsigned a1 = cvtpk(P[(B0) + 2], P[(B0) + 3]);                 \
      unsigned b0 = cvtpk(P[(B0) + 4], P[(B0) + 5]);                 \
      unsigned b1 = cvtpk(P[(B0) + 6], P[(B0) + 7]);                 \
      unsigned xa0 = __shfl_xor(a0, 32, 64);                         \
      unsigned xa1 = __shfl_xor(a1, 32, 64);                         \
      unsigned xb0 = __shfl_xor(b0, 32, 64);                         \
      unsigned xb1 = __shfl_xor(b1, 32, 64);                         \
      u32x4v fw;                                                     \
      fw[0] = hi ? xb0 : a0; fw[1] = hi ? xb1 : a1;                  \
      fw[2] = hi ? b0 : xa0; fw[3] = hi ? b1 : xa1;                  \
      dst = __builtin_bit_cast(bf16x8, fw); }
    BUILD_PA(pa0, p0, 0)
    BUILD_PA(pa1, p0, 8)
    BUILD_PA(pa2, p1, 0)
    BUILD_PA(pa3, p1, 8)
#undef BUILD_PA
    {
      const char* VsB = (const char*)&Vs[j & 1][0];
      __builtin_amdgcn_s_setprio(1);
#pragma unroll
      for (int dt = 0; dt < 4; ++dt) {
        const char* vrow = VsB + (dt * 32 + l31) * 128;
        bf16x8 v0 = *(const bf16x8*)(vrow + ((hi * 16) ^ swzV));
        bf16x8 v1 = *(const bf16x8*)(vrow + ((32 + hi * 16) ^ swzV));
        bf16x8 v2 = *(const bf16x8*)(vrow + ((64 + hi * 16) ^ swzV));
        bf16x8 v3 = *(const bf16x8*)(vrow + ((96 + hi * 16) ^ swzV));
        acc[dt] = MFMA32(v0, pa0, acc[dt]);
        acc[dt] = MFMA32(v1, pa1, acc[dt]);
        acc[dt] = MFMA32(v2, pa2, acc[dt]);
        acc[dt] = MFMA32(v3, pa3, acc[dt]);
      }
      __builtin_amdgcn_s_setprio(0);
    }
    __syncthreads();
    if (j + 2 < nj) stageV(j & 1, (j + 2) * 64);
    if (j + 3 < nj) stageK((j + 3) % 3, (j + 3) * 64);
    sc0 = sn0;
    sc1 = sn1;
  }
#undef QK_TILE
  float l = lpart + __shfl_xor(lpart, 32, 64);
  float invl = 1.0f / l;
  size_t orow_idx = (size_t)b * 2048 + h * 128 + (tq >> 4);
  bf16_t* orow = og + orow_idx * 2048 + (tq & 15) * 128;
#pragma unroll
  for (int dt = 0; dt < 4; ++dt)
#pragma unroll
    for (int g = 0; g < 4; ++g) {
      bf16x4 v4;
#pragma unroll
      for (int e = 0; e < 4; ++e) v4[e] = (bf16_t)(acc[dt][4 * g + e] * invl);
      *(bf16x4*)(orow + dt * 32 + 8 * g + 4 * hi) = v4;
    }
}

extern "C" void kernel_launch(void* const* d_in, const int* in_sizes, int n_in,
                              void* d_out, int out_size, void* d_ws, size_t ws_size,
                              hipStream_t stream) {
  const float* x = (const float*)d_in[0];      // [2,2048,2048]
  const float* wqkv = (const float*)d_in[1];   // [6144,2048]
  const float* wproj = (const float*)d_in[2];  // [2048,2048]
  float* out = (float*)d_out;                  // [2,2048,2048]
  char* ws = (char*)d_ws;

  const size_t OFF_WQKV = 16777216;
  const size_t OFF_WPROJ = 41943040;
  const size_t OFF_Q = 50331648;
  const size_t OFF_K = 67108864;
  const size_t OFF_VT = 83886080;

  bf16_t* xb = (bf16_t*)(ws);
  bf16_t* wqkvb = (bf16_t*)(ws + OFF_WQKV);
  bf16_t* wprojb = (bf16_t*)(ws + OFF_WPROJ);
  bf16_t* g_q = (bf16_t*)(ws + OFF_Q);
  bf16_t* g_k = (bf16_t*)(ws + OFF_K);
  bf16_t* g_vt = (bf16_t*)(ws + OFF_VT);
  bf16_t* g_att = (bf16_t*)(ws);               // alias xb (dead after gemms)

  cast_all<<<4096, 256, 0, stream>>>(x, wqkv, wproj, xb, wqkvb, wprojb);
  gemm_qkv<<<256, 512, 0, stream>>>(xb, wqkvb, g_q, g_k, 2048);
  gemm256<1><<<256, 512, 0, stream>>>(xb, wqkvb + (size_t)4096 * 2048, nullptr, g_vt,
                                      4096, 2048, 2048, 16, 4096);
  // attn v10: T15-pipelined, 512 blocks (heavy+light pairing) — session best
  attn_kernel<<<512, 256, 0, stream>>>(g_q, g_k, g_vt, g_att);
  gemm256<0><<<256, 512, 0, stream>>>(g_att, wprojb, out, nullptr, 4096, 2048, 2048, 16, 0);
}